// Round 1
// baseline (249.944 us; speedup 1.0000x reference)
//
#include <hip/hip_runtime.h>

typedef unsigned short u16;
typedef __attribute__((ext_vector_type(4))) unsigned short u16x4;
typedef __attribute__((ext_vector_type(8))) unsigned short u16x8;
typedef __attribute__((ext_vector_type(8))) short short8;
typedef __attribute__((ext_vector_type(4))) float f32x4;

#define NHEAD 16
#define HDIM 64
#define SEQ 2048
#define MODELD 1024
#define MROWS 4096            // B*N
#define QKVCOLS 3072

__device__ __forceinline__ u16 f2bf(float f) {
  union { float f; unsigned u; } v; v.f = f;
  unsigned r = v.u + 0x7FFFu + ((v.u >> 16) & 1u);
  return (u16)(r >> 16);
}

__device__ __forceinline__ void gload_lds16(const void* g, void* l) {
  __builtin_amdgcn_global_load_lds((const __attribute__((address_space(1))) void*)g,
                                   (__attribute__((address_space(3))) void*)l, 16, 0, 0);
}

// ---------------- prep kernels ----------------

// f32 -> bf16, 4 elems/thread, exact grid
__global__ void prep_cast(const float* __restrict__ in, u16* __restrict__ outb) {
  int i = blockIdx.x * 256 + threadIdx.x;
  float4 v = *(const float4*)(in + (size_t)i * 4);
  u16x4 o = {f2bf(v.x), f2bf(v.y), f2bf(v.z), f2bf(v.w)};
  *(u16x4*)(outb + (size_t)i * 4) = o;
}

// mask -> additive float; auto-detect int32 vs byte(bool) marshalling
__global__ void prep_mask(const unsigned int* __restrict__ mraw, float* __restrict__ mf) {
  __shared__ int is_bytes;
  if (threadIdx.x == 0) {
    int bytes = 0;
    for (int i = 0; i < 1024; ++i) { if (mraw[i] > 1u) { bytes = 1; break; } }
    is_bytes = bytes;
  }
  __syncthreads();
  const unsigned char* bp = (const unsigned char*)mraw;
  for (int i = threadIdx.x; i < 2 * SEQ; i += 256) {
    unsigned val = is_bytes ? (unsigned)bp[i] : mraw[i];
    mf[i] = val ? 0.f : -1e30f;
  }
}

// combined qkv weight (bf16) with LoRA + base fold; q rows pre-scaled by ATT_SCALE
__global__ void prep_w(const float* __restrict__ wqkv,
                       const float* __restrict__ wqb, const float* __restrict__ bq,
                       const float* __restrict__ wqA, const float* __restrict__ wqB,
                       const float* __restrict__ wvb, const float* __restrict__ bv,
                       const float* __restrict__ wvA, const float* __restrict__ wvB,
                       u16* __restrict__ wcomb, float* __restrict__ biasc) {
  const int c = blockIdx.x;             // 0..3071
  const int t = c >> 10, hd = c & 1023;
  const int k0 = threadIdx.x * 4;
  float4 w = *(const float4*)(wqkv + (size_t)c * MODELD + k0);
  float a0 = w.x, a1 = w.y, a2 = w.z, a3 = w.w;
  if (t != 1) {
    const float* base = (t == 0 ? wqb : wvb) + (size_t)hd * MODELD + k0;
    const float* A = (t == 0 ? wqA : wvA);
    const float* Bm = (t == 0 ? wqB : wvB) + hd * 10;
    float4 bsv = *(const float4*)base;
    a0 += bsv.x; a1 += bsv.y; a2 += bsv.z; a3 += bsv.w;
#pragma unroll
    for (int j = 0; j < 10; ++j) {
      float bj = Bm[j] * 0.1f;               // LORA_SCALE = 1/R
      float4 av = *(const float4*)(A + (size_t)j * MODELD + k0);
      a0 += bj * av.x; a1 += bj * av.y; a2 += bj * av.z; a3 += bj * av.w;
    }
    if (t == 0) { a0 *= 0.125f; a1 *= 0.125f; a2 *= 0.125f; a3 *= 0.125f; } // ATT_SCALE
  }
  u16x4 o = {f2bf(a0), f2bf(a1), f2bf(a2), f2bf(a3)};
  *(u16x4*)(wcomb + (size_t)c * MODELD + k0) = o;
  if (threadIdx.x == 0)
    biasc[c] = (t == 0) ? 0.125f * bq[hd] : ((t == 2) ? bv[hd] : 0.f);
}

// ---------------- 128x128 bf16 MFMA GEMM, BK=64, swizzled LDS ----------------
// C = A(bf16,[M][1024]) @ W(bf16,[Ncols][1024])^T ; MODE 0: scatter q/k/v, MODE 1: f32 + bias
template<int MODE>
__global__ __launch_bounds__(256) void gemm128(const u16* __restrict__ A, const u16* __restrict__ W,
                                               const float* __restrict__ bias,
                                               u16* __restrict__ oq, u16* __restrict__ ok, u16* __restrict__ ov,
                                               float* __restrict__ of) {
  __shared__ __align__(16) char lds[32768];
  const int tid = threadIdx.x;
  const int lane = tid & 63;
  const int wid = tid >> 6;
  const int wr = wid >> 1, wc = wid & 1;
  const int m0 = blockIdx.y << 7;
  const int n0 = blockIdx.x << 7;
  const int K = MODELD;

  f32x4 acc[4][4] = {};

  const int so = wid * 1024 + (lane << 4);
  for (int kt = 0; kt < K; kt += 64) {
#pragma unroll
    for (int c = 0; c < 4; ++c) {
      const int o = c * 4096 + so;
      const int row = o >> 7;
      const int colb = (o & 127) ^ ((row & 7) << 4);   // inverse-swizzled global source (m173)
      gload_lds16((const char*)(A + (size_t)(m0 + row) * K + kt) + colb, lds + (c * 4096 + wid * 1024));
      gload_lds16((const char*)(W + (size_t)(n0 + row) * K + kt) + colb, lds + (16384 + c * 4096 + wid * 1024));
    }
    __syncthreads();
#pragma unroll
    for (int ks = 0; ks < 2; ++ks) {
      short8 av[4], bv[4];
#pragma unroll
      for (int i = 0; i < 4; ++i) {
        const int arow = wr * 64 + i * 16 + (lane & 15);
        const int off = (ks * 64 + ((lane >> 4) << 4)) ^ ((lane & 7) << 4); // (row&7)==(lane&7)
        av[i] = *(const short8*)(lds + (arow << 7) + off);
        const int brow = wc * 64 + i * 16 + (lane & 15);
        bv[i] = *(const short8*)(lds + 16384 + (brow << 7) + off);
      }
#pragma unroll
      for (int i = 0; i < 4; ++i)
#pragma unroll
        for (int j = 0; j < 4; ++j)
          acc[i][j] = __builtin_amdgcn_mfma_f32_16x16x32_bf16(av[i], bv[j], acc[i][j], 0, 0, 0);
    }
    __syncthreads();
  }

  if (MODE == 0) {
#pragma unroll
    for (int j = 0; j < 4; ++j) {
      const int col = n0 + wc * 64 + j * 16 + (lane & 15);
      const int t = col >> 10;
      const int hd = col & 1023;
      const int h = hd >> 6, d = hd & 63;
      const float bs = bias[col];
      u16* dst = (t == 0) ? oq : ((t == 1) ? ok : ov);
#pragma unroll
      for (int i = 0; i < 4; ++i) {
        const int rowb = m0 + wr * 64 + i * 16 + ((lane >> 4) << 2);
#pragma unroll
        for (int r = 0; r < 4; ++r) {
          const int row = rowb + r;
          const int b = row >> 11, n = row & 2047;
          dst[((size_t)(b * NHEAD + h) * SEQ + n) * HDIM + d] = f2bf(acc[i][j][r] + bs);
        }
      }
    }
  } else {
#pragma unroll
    for (int j = 0; j < 4; ++j) {
      const int col = n0 + wc * 64 + j * 16 + (lane & 15);
      const float bs = bias[col];
#pragma unroll
      for (int i = 0; i < 4; ++i) {
        const int rowb = m0 + wr * 64 + i * 16 + ((lane >> 4) << 2);
#pragma unroll
        for (int r = 0; r < 4; ++r)
          of[(size_t)(rowb + r) * MODELD + col] = acc[i][j][r] + bs;
      }
    }
  }
}

// ---------------- V transpose: [bh][n][d] -> [bh][d][n] ----------------
__global__ void transpose_v(const u16* __restrict__ v, u16* __restrict__ vt) {
  __shared__ u16 lds[64][72];
  const int bh = blockIdx.y, n0 = blockIdx.x * 64;
  const int tid = threadIdx.x;
  const u16* src = v + (size_t)bh * SEQ * HDIM + (size_t)n0 * HDIM;
#pragma unroll
  for (int i = 0; i < 2; ++i) {
    int linear = tid * 8 + i * 2048;
    int row = linear >> 6, col = linear & 63;
    *(u16x8*)(&lds[row][col]) = *(const u16x8*)(src + row * 64 + col);
  }
  __syncthreads();
  u16* dst = vt + (size_t)bh * HDIM * SEQ + n0;
#pragma unroll
  for (int i = 0; i < 2; ++i) {
    int linear = tid * 8 + i * 2048;
    int d = linear >> 6, nc = linear & 63;
    u16x8 val;
#pragma unroll
    for (int j = 0; j < 8; ++j) val[j] = lds[nc + j][d];
    *(u16x8*)(dst + (size_t)d * SEQ + nc) = val;
  }
}

// ---------------- flash attention ----------------
// grid (N/64, B*H); 4 waves; wave w handles 16 q rows. q pre-scaled by ATT_SCALE.
__global__ __launch_bounds__(256) void flash_attn(const u16* __restrict__ q, const u16* __restrict__ k,
                                                  const u16* __restrict__ vt, const float* __restrict__ maskf,
                                                  u16* __restrict__ attnout) {
  __shared__ __align__(16) char lds[24576];   // K 8K | Vt 8K | P 4x2K
  const int tid = threadIdx.x;
  const int lane = tid & 63, wid = tid >> 6;
  const int bh = blockIdx.y;
  const int q0 = blockIdx.x * 64;
  const int b = bh >> 4, h = bh & 15;
  const size_t headoff = (size_t)bh * (SEQ * HDIM);

  short8 aq[2];
  {
    const u16* qp = q + headoff + (size_t)(q0 + wid * 16 + (lane & 15)) * HDIM + ((lane >> 4) << 3);
    aq[0] = *(const short8*)qp;
    aq[1] = *(const short8*)(qp + 32);
  }
  float mrun[4] = {-1e30f, -1e30f, -1e30f, -1e30f};
  float lsum[4] = {0.f, 0.f, 0.f, 0.f};
  f32x4 oacc[4] = {};

  char* Ks = lds;
  char* Vs = lds + 8192;
  char* Ps = lds + 16384 + wid * 2048;
  const float* mrow = maskf + b * SEQ;

  for (int kv0 = 0; kv0 < SEQ; kv0 += 64) {
#pragma unroll
    for (int c = 0; c < 2; ++c) {
      const int o = c * 4096 + wid * 1024 + (lane << 4);
      const int row = o >> 7;
      const int colb = (o & 127) ^ ((row & 7) << 4);
      gload_lds16((const char*)(k + headoff + (size_t)(kv0 + row) * HDIM) + colb, Ks + c * 4096 + wid * 1024);
      gload_lds16((const char*)(vt + headoff + (size_t)row * SEQ + kv0) + colb, Vs + c * 4096 + wid * 1024);
    }
    __syncthreads();

    f32x4 s[4] = {};
#pragma unroll
    for (int ks = 0; ks < 2; ++ks)
#pragma unroll
      for (int n = 0; n < 4; ++n) {
        const int krow = n * 16 + (lane & 15);
        const int koff = (ks * 64 + ((lane >> 4) << 4)) ^ ((krow & 7) << 4);
        short8 bk = *(const short8*)(Ks + (krow << 7) + koff);
        s[n] = __builtin_amdgcn_mfma_f32_16x16x32_bf16(aq[ks], bk, s[n], 0, 0, 0);
      }

    float mk[4];
#pragma unroll
    for (int n = 0; n < 4; ++n) mk[n] = mrow[kv0 + n * 16 + (lane & 15)];

    float alpha[4];
#pragma unroll
    for (int r = 0; r < 4; ++r) {
      float s0 = s[0][r] + mk[0], s1 = s[1][r] + mk[1];
      float s2 = s[2][r] + mk[2], s3 = s[3][r] + mk[3];
      float mx = fmaxf(fmaxf(s0, s1), fmaxf(s2, s3));
      mx = fmaxf(mx, __shfl_xor(mx, 1));
      mx = fmaxf(mx, __shfl_xor(mx, 2));
      mx = fmaxf(mx, __shfl_xor(mx, 4));
      mx = fmaxf(mx, __shfl_xor(mx, 8));
      const float mn = fmaxf(mrun[r], mx);
      alpha[r] = __expf(mrun[r] - mn);
      mrun[r] = mn;
      float p0 = __expf(s0 - mn), p1 = __expf(s1 - mn);
      float p2 = __expf(s2 - mn), p3 = __expf(s3 - mn);
      s[0][r] = p0; s[1][r] = p1; s[2][r] = p2; s[3][r] = p3;
      float rsum = (p0 + p1) + (p2 + p3);
      rsum += __shfl_xor(rsum, 1);
      rsum += __shfl_xor(rsum, 2);
      rsum += __shfl_xor(rsum, 4);
      rsum += __shfl_xor(rsum, 8);
      lsum[r] = lsum[r] * alpha[r] + rsum;
    }
    // P -> per-wave LDS (swizzled), bf16
#pragma unroll
    for (int r = 0; r < 4; ++r) {
      const int prow = ((lane >> 4) << 2) + r;
      const int pxor = (prow & 7) << 4;
#pragma unroll
      for (int n = 0; n < 4; ++n) {
        const int off = (prow << 7) + ((n * 32 + ((lane & 15) << 1)) ^ pxor);
        *(u16*)(Ps + off) = f2bf(s[n][r]);
      }
    }
#pragma unroll
    for (int nd = 0; nd < 4; ++nd) {
      oacc[nd][0] *= alpha[0]; oacc[nd][1] *= alpha[1];
      oacc[nd][2] *= alpha[2]; oacc[nd][3] *= alpha[3];
    }
    // O += P @ V
#pragma unroll
    for (int ks = 0; ks < 2; ++ks) {
      const int prow = lane & 15;
      const int poff = (prow << 7) + ((ks * 64 + ((lane >> 4) << 4)) ^ ((prow & 7) << 4));
      short8 ap = *(const short8*)(Ps + poff);
#pragma unroll
      for (int nd = 0; nd < 4; ++nd) {
        const int vrow = nd * 16 + (lane & 15);
        const int voff = (ks * 64 + ((lane >> 4) << 4)) ^ ((vrow & 7) << 4);
        short8 bv = *(const short8*)(Vs + (vrow << 7) + voff);
        oacc[nd] = __builtin_amdgcn_mfma_f32_16x16x32_bf16(ap, bv, oacc[nd], 0, 0, 0);
      }
    }
    __syncthreads();
  }

  float inv[4];
#pragma unroll
  for (int r = 0; r < 4; ++r) inv[r] = 1.0f / lsum[r];
  u16* outp = attnout + (size_t)(b * SEQ + q0 + wid * 16) * MODELD + h * HDIM;
#pragma unroll
  for (int nd = 0; nd < 4; ++nd)
#pragma unroll
    for (int r = 0; r < 4; ++r) {
      const int row = ((lane >> 4) << 2) + r;
      outp[(size_t)row * MODELD + nd * 16 + (lane & 15)] = f2bf(oacc[nd][r] * inv[r]);
    }
}

// ---------------- launch ----------------
extern "C" void kernel_launch(void* const* d_in, const int* in_sizes, int n_in,
                              void* d_out, int out_size, void* d_ws, size_t ws_size,
                              hipStream_t stream) {
  const float* x       = (const float*)d_in[0];
  const unsigned int* mask = (const unsigned int*)d_in[1];
  const float* w_qkv   = (const float*)d_in[2];
  const float* wq_base = (const float*)d_in[3];
  const float* bq      = (const float*)d_in[4];
  const float* wq_A    = (const float*)d_in[5];
  const float* wq_B    = (const float*)d_in[6];
  const float* wv_base = (const float*)d_in[7];
  const float* bv      = (const float*)d_in[8];
  const float* wv_A    = (const float*)d_in[9];
  const float* wv_B    = (const float*)d_in[10];
  const float* w_out   = (const float*)d_in[11];
  const float* b_out   = (const float*)d_in[12];
  float* out = (float*)d_out;

  char* ws = (char*)d_ws;
  u16* xb      = (u16*)(ws);                 // 8 MB  (reused as attnout)
  u16* wcomb   = (u16*)(ws + 8388608);       // 6 MB
  u16* woutb   = (u16*)(ws + 14680064);      // 2 MB
  u16* qws     = (u16*)(ws + 16777216);      // 8 MB
  u16* kws     = (u16*)(ws + 25165824);      // 8 MB
  u16* vws     = (u16*)(ws + 33554432);      // 8 MB
  u16* vtws    = (u16*)(ws + 41943040);      // 8 MB
  float* biasc = (float*)(ws + 50331648);    // 12 KB
  float* maskf = (float*)(ws + 50343936);    // 16 KB
  u16* attnout = xb;                          // xb dead after gemm_qkv

  prep_cast<<<4096, 256, 0, stream>>>(x, xb);          // 4M elems
  prep_cast<<<1024, 256, 0, stream>>>(w_out, woutb);   // 1M elems
  prep_mask<<<1, 256, 0, stream>>>(mask, maskf);
  prep_w<<<3072, 256, 0, stream>>>(w_qkv, wq_base, bq, wq_A, wq_B,
                                   wv_base, bv, wv_A, wv_B, wcomb, biasc);

  gemm128<0><<<dim3(QKVCOLS / 128, MROWS / 128), 256, 0, stream>>>(
      xb, wcomb, biasc, qws, kws, vws, nullptr);

  transpose_v<<<dim3(SEQ / 64, 32), 256, 0, stream>>>(vws, vtws);

  flash_attn<<<dim3(SEQ / 64, 32), 256, 0, stream>>>(qws, kws, vtws, maskf, attnout);

  gemm128<1><<<dim3(MODELD / 128, MROWS / 128), 256, 0, stream>>>(
      attnout, woutb, b_out, nullptr, nullptr, nullptr, out);
}

// Round 2
// 249.036 us; speedup vs baseline: 1.0036x; 1.0036x over previous
//
#include <hip/hip_runtime.h>

typedef unsigned short u16;
typedef __attribute__((ext_vector_type(4))) unsigned short u16x4;
typedef __attribute__((ext_vector_type(8))) unsigned short u16x8;
typedef __attribute__((ext_vector_type(8))) short short8;
typedef __attribute__((ext_vector_type(4))) float f32x4;

#define NHEAD 16
#define HDIM 64
#define SEQ 2048
#define MODELD 1024
#define MROWS 4096            // B*N
#define QKVCOLS 3072

__device__ __forceinline__ u16 f2bf(float f) {
  union { float f; unsigned u; } v; v.f = f;
  unsigned r = v.u + 0x7FFFu + ((v.u >> 16) & 1u);
  return (u16)(r >> 16);
}

__device__ __forceinline__ void gload_lds16(const void* g, void* l) {
  __builtin_amdgcn_global_load_lds((const __attribute__((address_space(1))) void*)g,
                                   (__attribute__((address_space(3))) void*)l, 16, 0, 0);
}

// ---------------- prep kernels ----------------

// f32 -> bf16, 4 elems/thread, exact grid
__global__ void prep_cast(const float* __restrict__ in, u16* __restrict__ outb) {
  int i = blockIdx.x * 256 + threadIdx.x;
  float4 v = *(const float4*)(in + (size_t)i * 4);
  u16x4 o = {f2bf(v.x), f2bf(v.y), f2bf(v.z), f2bf(v.w)};
  *(u16x4*)(outb + (size_t)i * 4) = o;
}

// mask -> additive float; auto-detect int32 vs byte(bool) marshalling
__global__ void prep_mask(const unsigned int* __restrict__ mraw, float* __restrict__ mf) {
  __shared__ int is_bytes;
  if (threadIdx.x == 0) {
    int bytes = 0;
    for (int i = 0; i < 1024; ++i) { if (mraw[i] > 1u) { bytes = 1; break; } }
    is_bytes = bytes;
  }
  __syncthreads();
  const unsigned char* bp = (const unsigned char*)mraw;
  for (int i = threadIdx.x; i < 2 * SEQ; i += 256) {
    unsigned val = is_bytes ? (unsigned)bp[i] : mraw[i];
    mf[i] = val ? 0.f : -1e30f;
  }
}

// combined qkv weight (bf16) with LoRA + base fold; q rows pre-scaled by ATT_SCALE
__global__ void prep_w(const float* __restrict__ wqkv,
                       const float* __restrict__ wqb, const float* __restrict__ bq,
                       const float* __restrict__ wqA, const float* __restrict__ wqB,
                       const float* __restrict__ wvb, const float* __restrict__ bv,
                       const float* __restrict__ wvA, const float* __restrict__ wvB,
                       u16* __restrict__ wcomb, float* __restrict__ biasc) {
  const int c = blockIdx.x;             // 0..3071
  const int t = c >> 10, hd = c & 1023;
  const int k0 = threadIdx.x * 4;
  float4 w = *(const float4*)(wqkv + (size_t)c * MODELD + k0);
  float a0 = w.x, a1 = w.y, a2 = w.z, a3 = w.w;
  if (t != 1) {
    const float* base = (t == 0 ? wqb : wvb) + (size_t)hd * MODELD + k0;
    const float* A = (t == 0 ? wqA : wvA);
    const float* Bm = (t == 0 ? wqB : wvB) + hd * 10;
    float4 bsv = *(const float4*)base;
    a0 += bsv.x; a1 += bsv.y; a2 += bsv.z; a3 += bsv.w;
#pragma unroll
    for (int j = 0; j < 10; ++j) {
      float bj = Bm[j] * 0.1f;               // LORA_SCALE = 1/R
      float4 av = *(const float4*)(A + (size_t)j * MODELD + k0);
      a0 += bj * av.x; a1 += bj * av.y; a2 += bj * av.z; a3 += bj * av.w;
    }
    if (t == 0) { a0 *= 0.125f; a1 *= 0.125f; a2 *= 0.125f; a3 *= 0.125f; } // ATT_SCALE
  }
  u16x4 o = {f2bf(a0), f2bf(a1), f2bf(a2), f2bf(a3)};
  *(u16x4*)(wcomb + (size_t)c * MODELD + k0) = o;
  if (threadIdx.x == 0)
    biasc[c] = (t == 0) ? 0.125f * bq[hd] : ((t == 2) ? bv[hd] : 0.f);
}

// ---------------- 128x128 bf16 MFMA GEMM, BK=64, swizzled LDS ----------------
// C = A(bf16,[M][1024]) @ W(bf16,[Ncols][1024])^T ; MODE 0: scatter q/k/v, MODE 1: f32 + bias
template<int MODE>
__global__ __launch_bounds__(256) void gemm128(const u16* __restrict__ A, const u16* __restrict__ W,
                                               const float* __restrict__ bias,
                                               u16* __restrict__ oq, u16* __restrict__ ok, u16* __restrict__ ov,
                                               float* __restrict__ of) {
  __shared__ __align__(16) char lds[32768];
  const int tid = threadIdx.x;
  const int lane = tid & 63;
  const int wid = tid >> 6;
  const int wr = wid >> 1, wc = wid & 1;
  const int m0 = blockIdx.y << 7;
  const int n0 = blockIdx.x << 7;
  const int K = MODELD;

  f32x4 acc[4][4] = {};

  const int so = wid * 1024 + (lane << 4);
  for (int kt = 0; kt < K; kt += 64) {
#pragma unroll
    for (int c = 0; c < 4; ++c) {
      const int o = c * 4096 + so;
      const int row = o >> 7;
      const int colb = (o & 127) ^ ((row & 7) << 4);   // inverse-swizzled global source (m173)
      gload_lds16((const char*)(A + (size_t)(m0 + row) * K + kt) + colb, lds + (c * 4096 + wid * 1024));
      gload_lds16((const char*)(W + (size_t)(n0 + row) * K + kt) + colb, lds + (16384 + c * 4096 + wid * 1024));
    }
    __syncthreads();
#pragma unroll
    for (int ks = 0; ks < 2; ++ks) {
      short8 av[4], bv[4];
#pragma unroll
      for (int i = 0; i < 4; ++i) {
        const int arow = wr * 64 + i * 16 + (lane & 15);
        const int off = (ks * 64 + ((lane >> 4) << 4)) ^ ((lane & 7) << 4); // (row&7)==(lane&7)
        av[i] = *(const short8*)(lds + (arow << 7) + off);
        const int brow = wc * 64 + i * 16 + (lane & 15);
        bv[i] = *(const short8*)(lds + 16384 + (brow << 7) + off);
      }
#pragma unroll
      for (int i = 0; i < 4; ++i)
#pragma unroll
        for (int j = 0; j < 4; ++j)
          acc[i][j] = __builtin_amdgcn_mfma_f32_16x16x32_bf16(av[i], bv[j], acc[i][j], 0, 0, 0);
    }
    __syncthreads();
  }

  if (MODE == 0) {
#pragma unroll
    for (int j = 0; j < 4; ++j) {
      const int col = n0 + wc * 64 + j * 16 + (lane & 15);
      const int t = col >> 10;
      const int hd = col & 1023;
      const int h = hd >> 6, d = hd & 63;
      const float bs = bias[col];
      u16* dst = (t == 0) ? oq : ((t == 1) ? ok : ov);
#pragma unroll
      for (int i = 0; i < 4; ++i) {
        const int rowb = m0 + wr * 64 + i * 16 + ((lane >> 4) << 2);
#pragma unroll
        for (int r = 0; r < 4; ++r) {
          const int row = rowb + r;
          const int b = row >> 11, n = row & 2047;
          dst[((size_t)(b * NHEAD + h) * SEQ + n) * HDIM + d] = f2bf(acc[i][j][r] + bs);
        }
      }
    }
  } else {
#pragma unroll
    for (int j = 0; j < 4; ++j) {
      const int col = n0 + wc * 64 + j * 16 + (lane & 15);
      const float bs = bias[col];
#pragma unroll
      for (int i = 0; i < 4; ++i) {
        const int rowb = m0 + wr * 64 + i * 16 + ((lane >> 4) << 2);
#pragma unroll
        for (int r = 0; r < 4; ++r)
          of[(size_t)(rowb + r) * MODELD + col] = acc[i][j][r] + bs;
      }
    }
  }
}

// ---------------- V transpose: [bh][n][d] -> [bh][d][n] ----------------
__global__ void transpose_v(const u16* __restrict__ v, u16* __restrict__ vt) {
  __shared__ u16 lds[64][72];
  const int bh = blockIdx.y, n0 = blockIdx.x * 64;
  const int tid = threadIdx.x;
  const u16* src = v + (size_t)bh * SEQ * HDIM + (size_t)n0 * HDIM;
#pragma unroll
  for (int i = 0; i < 2; ++i) {
    int linear = tid * 8 + i * 2048;
    int row = linear >> 6, col = linear & 63;
    *(u16x8*)(&lds[row][col]) = *(const u16x8*)(src + row * 64 + col);
  }
  __syncthreads();
  u16* dst = vt + (size_t)bh * HDIM * SEQ + n0;
#pragma unroll
  for (int i = 0; i < 2; ++i) {
    int linear = tid * 8 + i * 2048;
    int d = linear >> 6, nc = linear & 63;
    u16x8 val;
#pragma unroll
    for (int j = 0; j < 8; ++j) val[j] = lds[nc + j][d];
    *(u16x8*)(dst + (size_t)d * SEQ + nc) = val;
  }
}

// ---------------- flash attention ----------------
// grid (N/64, B*H); 4 waves; wave w handles 16 q rows. q pre-scaled by ATT_SCALE.
__global__ __launch_bounds__(256) void flash_attn(const u16* __restrict__ q, const u16* __restrict__ k,
                                                  const u16* __restrict__ vt, const float* __restrict__ maskf,
                                                  u16* __restrict__ attnout) {
  __shared__ __align__(16) char lds[24576];   // K 8K | Vt 8K | P 4x2K
  const int tid = threadIdx.x;
  const int lane = tid & 63, wid = tid >> 6;
  const int bh = blockIdx.y;
  const int q0 = blockIdx.x * 64;
  const int b = bh >> 4, h = bh & 15;
  const size_t headoff = (size_t)bh * (SEQ * HDIM);

  short8 aq[2];
  {
    const u16* qp = q + headoff + (size_t)(q0 + wid * 16 + (lane & 15)) * HDIM + ((lane >> 4) << 3);
    aq[0] = *(const short8*)qp;
    aq[1] = *(const short8*)(qp + 32);
  }
  float mrun[4] = {-1e30f, -1e30f, -1e30f, -1e30f};
  float lsum[4] = {0.f, 0.f, 0.f, 0.f};
  f32x4 oacc[4] = {};

  char* Ks = lds;
  char* Vs = lds + 8192;
  char* Ps = lds + 16384 + wid * 2048;
  const float* mrow = maskf + b * SEQ;

  for (int kv0 = 0; kv0 < SEQ; kv0 += 64) {
#pragma unroll
    for (int c = 0; c < 2; ++c) {
      const int o = c * 4096 + wid * 1024 + (lane << 4);
      const int row = o >> 7;
      const int colb = (o & 127) ^ ((row & 7) << 4);
      gload_lds16((const char*)(k + headoff + (size_t)(kv0 + row) * HDIM) + colb, Ks + c * 4096 + wid * 1024);
      gload_lds16((const char*)(vt + headoff + (size_t)row * SEQ + kv0) + colb, Vs + c * 4096 + wid * 1024);
    }
    __syncthreads();

    f32x4 s[4] = {};
#pragma unroll
    for (int ks = 0; ks < 2; ++ks)
#pragma unroll
      for (int n = 0; n < 4; ++n) {
        const int krow = n * 16 + (lane & 15);
        const int koff = (ks * 64 + ((lane >> 4) << 4)) ^ ((krow & 7) << 4);
        short8 bk = *(const short8*)(Ks + (krow << 7) + koff);
        s[n] = __builtin_amdgcn_mfma_f32_16x16x32_bf16(aq[ks], bk, s[n], 0, 0, 0);
      }

    float mk[4];
#pragma unroll
    for (int n = 0; n < 4; ++n) mk[n] = mrow[kv0 + n * 16 + (lane & 15)];

    float alpha[4];
#pragma unroll
    for (int r = 0; r < 4; ++r) {
      float s0 = s[0][r] + mk[0], s1 = s[1][r] + mk[1];
      float s2 = s[2][r] + mk[2], s3 = s[3][r] + mk[3];
      float mx = fmaxf(fmaxf(s0, s1), fmaxf(s2, s3));
      mx = fmaxf(mx, __shfl_xor(mx, 1));
      mx = fmaxf(mx, __shfl_xor(mx, 2));
      mx = fmaxf(mx, __shfl_xor(mx, 4));
      mx = fmaxf(mx, __shfl_xor(mx, 8));
      const float mn = fmaxf(mrun[r], mx);
      alpha[r] = __expf(mrun[r] - mn);
      mrun[r] = mn;
      float p0 = __expf(s0 - mn), p1 = __expf(s1 - mn);
      float p2 = __expf(s2 - mn), p3 = __expf(s3 - mn);
      s[0][r] = p0; s[1][r] = p1; s[2][r] = p2; s[3][r] = p3;
      float rsum = (p0 + p1) + (p2 + p3);
      rsum += __shfl_xor(rsum, 1);
      rsum += __shfl_xor(rsum, 2);
      rsum += __shfl_xor(rsum, 4);
      rsum += __shfl_xor(rsum, 8);
      lsum[r] = lsum[r] * alpha[r] + rsum;
    }
    // P -> per-wave LDS (swizzled), bf16
#pragma unroll
    for (int r = 0; r < 4; ++r) {
      const int prow = ((lane >> 4) << 2) + r;
      const int pxor = (prow & 7) << 4;
#pragma unroll
      for (int n = 0; n < 4; ++n) {
        const int off = (prow << 7) + ((n * 32 + ((lane & 15) << 1)) ^ pxor);
        *(u16*)(Ps + off) = f2bf(s[n][r]);
      }
    }
#pragma unroll
    for (int nd = 0; nd < 4; ++nd) {
      oacc[nd][0] *= alpha[0]; oacc[nd][1] *= alpha[1];
      oacc[nd][2] *= alpha[2]; oacc[nd][3] *= alpha[3];
    }
    // O += P @ V
#pragma unroll
    for (int ks = 0; ks < 2; ++ks) {
      const int prow = lane & 15;
      const int poff = (prow << 7) + ((ks * 64 + ((lane >> 4) << 4)) ^ ((prow & 7) << 4));
      short8 ap = *(const short8*)(Ps + poff);
#pragma unroll
      for (int nd = 0; nd < 4; ++nd) {
        const int vrow = nd * 16 + (lane & 15);
        const int voff = (ks * 64 + ((lane >> 4) << 4)) ^ ((vrow & 7) << 4);
        short8 bv = *(const short8*)(Vs + (vrow << 7) + voff);
        oacc[nd] = __builtin_amdgcn_mfma_f32_16x16x32_bf16(ap, bv, oacc[nd], 0, 0, 0);
      }
    }
    __syncthreads();
  }

  float inv[4];
#pragma unroll
  for (int r = 0; r < 4; ++r) inv[r] = 1.0f / lsum[r];
  u16* outp = attnout + (size_t)(b * SEQ + q0 + wid * 16) * MODELD + h * HDIM;
#pragma unroll
  for (int nd = 0; nd < 4; ++nd)
#pragma unroll
    for (int r = 0; r < 4; ++r) {
      const int row = ((lane >> 4) << 2) + r;
      outp[(size_t)row * MODELD + nd * 16 + (lane & 15)] = f2bf(oacc[nd][r] * inv[r]);
    }
}

// ---------------- launch ----------------
extern "C" void kernel_launch(void* const* d_in, const int* in_sizes, int n_in,
                              void* d_out, int out_size, void* d_ws, size_t ws_size,
                              hipStream_t stream) {
  const float* x       = (const float*)d_in[0];
  const unsigned int* mask = (const unsigned int*)d_in[1];
  const float* w_qkv   = (const float*)d_in[2];
  const float* wq_base = (const float*)d_in[3];
  const float* bq      = (const float*)d_in[4];
  const float* wq_A    = (const float*)d_in[5];
  const float* wq_B    = (const float*)d_in[6];
  const float* wv_base = (const float*)d_in[7];
  const float* bv      = (const float*)d_in[8];
  const float* wv_A    = (const float*)d_in[9];
  const float* wv_B    = (const float*)d_in[10];
  const float* w_out   = (const float*)d_in[11];
  const float* b_out   = (const float*)d_in[12];
  float* out = (float*)d_out;

  char* ws = (char*)d_ws;
  u16* xb      = (u16*)(ws);                 // 8 MB  (reused as attnout)
  u16* wcomb   = (u16*)(ws + 8388608);       // 6 MB
  u16* woutb   = (u16*)(ws + 14680064);      // 2 MB
  u16* qws     = (u16*)(ws + 16777216);      // 8 MB
  u16* kws     = (u16*)(ws + 25165824);      // 8 MB
  u16* vws     = (u16*)(ws + 33554432);      // 8 MB
  u16* vtws    = (u16*)(ws + 41943040);      // 8 MB
  float* biasc = (float*)(ws + 50331648);    // 12 KB
  float* maskf = (float*)(ws + 50343936);    // 16 KB
  u16* attnout = xb;                          // xb dead after gemm_qkv

  prep_cast<<<4096, 256, 0, stream>>>(x, xb);          // 4M elems
  prep_cast<<<1024, 256, 0, stream>>>(w_out, woutb);   // 1M elems
  prep_mask<<<1, 256, 0, stream>>>(mask, maskf);
  prep_w<<<3072, 256, 0, stream>>>(w_qkv, wq_base, bq, wq_A, wq_B,
                                   wv_base, bv, wv_A, wv_B, wcomb, biasc);

  gemm128<0><<<dim3(QKVCOLS / 128, MROWS / 128), 256, 0, stream>>>(
      xb, wcomb, biasc, qws, kws, vws, nullptr);

  transpose_v<<<dim3(SEQ / 64, 32), 256, 0, stream>>>(vws, vtws);

  flash_attn<<<dim3(SEQ / 64, 32), 256, 0, stream>>>(qws, kws, vtws, maskf, attnout);

  gemm128<1><<<dim3(MODELD / 128, MROWS / 128), 256, 0, stream>>>(
      attnout, woutb, b_out, nullptr, nullptr, nullptr, out);
}

// Round 3
// 248.929 us; speedup vs baseline: 1.0041x; 1.0004x over previous
//
#include <hip/hip_runtime.h>

typedef unsigned short u16;
typedef __attribute__((ext_vector_type(4))) unsigned short u16x4;
typedef __attribute__((ext_vector_type(8))) unsigned short u16x8;
typedef __attribute__((ext_vector_type(8))) short short8;
typedef __attribute__((ext_vector_type(4))) float f32x4;

#define NHEAD 16
#define HDIM 64
#define SEQ 2048
#define MODELD 1024
#define MROWS 4096            // B*N
#define QKVCOLS 3072

__device__ __forceinline__ u16 f2bf(float f) {
  union { float f; unsigned u; } v; v.f = f;
  unsigned r = v.u + 0x7FFFu + ((v.u >> 16) & 1u);
  return (u16)(r >> 16);
}

__device__ __forceinline__ void gload_lds16(const void* g, void* l) {
  __builtin_amdgcn_global_load_lds((const __attribute__((address_space(1))) void*)g,
                                   (__attribute__((address_space(3))) void*)l, 16, 0, 0);
}

// ---------------- prep kernels ----------------

// f32 -> bf16, 4 elems/thread, exact grid
__global__ void prep_cast(const float* __restrict__ in, u16* __restrict__ outb) {
  int i = blockIdx.x * 256 + threadIdx.x;
  float4 v = *(const float4*)(in + (size_t)i * 4);
  u16x4 o = {f2bf(v.x), f2bf(v.y), f2bf(v.z), f2bf(v.w)};
  *(u16x4*)(outb + (size_t)i * 4) = o;
}

// mask -> additive float; auto-detect int32 vs byte(bool) marshalling
__global__ void prep_mask(const unsigned int* __restrict__ mraw, float* __restrict__ mf) {
  __shared__ int is_bytes;
  if (threadIdx.x == 0) {
    int bytes = 0;
    for (int i = 0; i < 1024; ++i) { if (mraw[i] > 1u) { bytes = 1; break; } }
    is_bytes = bytes;
  }
  __syncthreads();
  const unsigned char* bp = (const unsigned char*)mraw;
  for (int i = threadIdx.x; i < 2 * SEQ; i += 256) {
    unsigned val = is_bytes ? (unsigned)bp[i] : mraw[i];
    mf[i] = val ? 0.f : -1e30f;
  }
}

// combined qkv weight (bf16) with LoRA + base fold; q rows pre-scaled by ATT_SCALE
__global__ void prep_w(const float* __restrict__ wqkv,
                       const float* __restrict__ wqb, const float* __restrict__ bq,
                       const float* __restrict__ wqA, const float* __restrict__ wqB,
                       const float* __restrict__ wvb, const float* __restrict__ bv,
                       const float* __restrict__ wvA, const float* __restrict__ wvB,
                       u16* __restrict__ wcomb, float* __restrict__ biasc) {
  const int c = blockIdx.x;             // 0..3071
  const int t = c >> 10, hd = c & 1023;
  const int k0 = threadIdx.x * 4;
  float4 w = *(const float4*)(wqkv + (size_t)c * MODELD + k0);
  float a0 = w.x, a1 = w.y, a2 = w.z, a3 = w.w;
  if (t != 1) {
    const float* base = (t == 0 ? wqb : wvb) + (size_t)hd * MODELD + k0;
    const float* A = (t == 0 ? wqA : wvA);
    const float* Bm = (t == 0 ? wqB : wvB) + hd * 10;
    float4 bsv = *(const float4*)base;
    a0 += bsv.x; a1 += bsv.y; a2 += bsv.z; a3 += bsv.w;
#pragma unroll
    for (int j = 0; j < 10; ++j) {
      float bj = Bm[j] * 0.1f;               // LORA_SCALE = 1/R
      float4 av = *(const float4*)(A + (size_t)j * MODELD + k0);
      a0 += bj * av.x; a1 += bj * av.y; a2 += bj * av.z; a3 += bj * av.w;
    }
    if (t == 0) { a0 *= 0.125f; a1 *= 0.125f; a2 *= 0.125f; a3 *= 0.125f; } // ATT_SCALE
  }
  u16x4 o = {f2bf(a0), f2bf(a1), f2bf(a2), f2bf(a3)};
  *(u16x4*)(wcomb + (size_t)c * MODELD + k0) = o;
  if (threadIdx.x == 0)
    biasc[c] = (t == 0) ? 0.125f * bq[hd] : ((t == 2) ? bv[hd] : 0.f);
}

// ---------------- 128x128 bf16 MFMA GEMM, BK=64, swizzled LDS ----------------
// C = A(bf16,[M][1024]) @ W(bf16,[Ncols][1024])^T ; MODE 0: scatter q/k/v, MODE 1: f32 + bias
template<int MODE>
__global__ __launch_bounds__(256) void gemm128(const u16* __restrict__ A, const u16* __restrict__ W,
                                               const float* __restrict__ bias,
                                               u16* __restrict__ oq, u16* __restrict__ ok, u16* __restrict__ ov,
                                               float* __restrict__ of) {
  __shared__ __align__(16) char lds[32768];
  const int tid = threadIdx.x;
  const int lane = tid & 63;
  const int wid = tid >> 6;
  const int wr = wid >> 1, wc = wid & 1;
  const int m0 = blockIdx.y << 7;
  const int n0 = blockIdx.x << 7;
  const int K = MODELD;

  f32x4 acc[4][4] = {};

  const int so = wid * 1024 + (lane << 4);
  for (int kt = 0; kt < K; kt += 64) {
#pragma unroll
    for (int c = 0; c < 4; ++c) {
      const int o = c * 4096 + so;
      const int row = o >> 7;
      const int colb = (o & 127) ^ ((row & 7) << 4);   // inverse-swizzled global source (m173)
      gload_lds16((const char*)(A + (size_t)(m0 + row) * K + kt) + colb, lds + (c * 4096 + wid * 1024));
      gload_lds16((const char*)(W + (size_t)(n0 + row) * K + kt) + colb, lds + (16384 + c * 4096 + wid * 1024));
    }
    __syncthreads();
#pragma unroll
    for (int ks = 0; ks < 2; ++ks) {
      short8 av[4], bv[4];
#pragma unroll
      for (int i = 0; i < 4; ++i) {
        const int arow = wr * 64 + i * 16 + (lane & 15);
        const int off = (ks * 64 + ((lane >> 4) << 4)) ^ ((lane & 7) << 4); // (row&7)==(lane&7)
        av[i] = *(const short8*)(lds + (arow << 7) + off);
        const int brow = wc * 64 + i * 16 + (lane & 15);
        bv[i] = *(const short8*)(lds + 16384 + (brow << 7) + off);
      }
#pragma unroll
      for (int i = 0; i < 4; ++i)
#pragma unroll
        for (int j = 0; j < 4; ++j)
          acc[i][j] = __builtin_amdgcn_mfma_f32_16x16x32_bf16(av[i], bv[j], acc[i][j], 0, 0, 0);
    }
    __syncthreads();
  }

  if (MODE == 0) {
#pragma unroll
    for (int j = 0; j < 4; ++j) {
      const int col = n0 + wc * 64 + j * 16 + (lane & 15);
      const int t = col >> 10;
      const int hd = col & 1023;
      const int h = hd >> 6, d = hd & 63;
      const float bs = bias[col];
      u16* dst = (t == 0) ? oq : ((t == 1) ? ok : ov);
#pragma unroll
      for (int i = 0; i < 4; ++i) {
        const int rowb = m0 + wr * 64 + i * 16 + ((lane >> 4) << 2);
#pragma unroll
        for (int r = 0; r < 4; ++r) {
          const int row = rowb + r;
          const int b = row >> 11, n = row & 2047;
          dst[((size_t)(b * NHEAD + h) * SEQ + n) * HDIM + d] = f2bf(acc[i][j][r] + bs);
        }
      }
    }
  } else {
#pragma unroll
    for (int j = 0; j < 4; ++j) {
      const int col = n0 + wc * 64 + j * 16 + (lane & 15);
      const float bs = bias[col];
#pragma unroll
      for (int i = 0; i < 4; ++i) {
        const int rowb = m0 + wr * 64 + i * 16 + ((lane >> 4) << 2);
#pragma unroll
        for (int r = 0; r < 4; ++r)
          of[(size_t)(rowb + r) * MODELD + col] = acc[i][j][r] + bs;
      }
    }
  }
}

// ---------------- V transpose: [bh][n][d] -> [bh][d][n] ----------------
__global__ void transpose_v(const u16* __restrict__ v, u16* __restrict__ vt) {
  __shared__ u16 lds[64][72];
  const int bh = blockIdx.y, n0 = blockIdx.x * 64;
  const int tid = threadIdx.x;
  const u16* src = v + (size_t)bh * SEQ * HDIM + (size_t)n0 * HDIM;
#pragma unroll
  for (int i = 0; i < 2; ++i) {
    int linear = tid * 8 + i * 2048;
    int row = linear >> 6, col = linear & 63;
    *(u16x8*)(&lds[row][col]) = *(const u16x8*)(src + row * 64 + col);
  }
  __syncthreads();
  u16* dst = vt + (size_t)bh * HDIM * SEQ + n0;
#pragma unroll
  for (int i = 0; i < 2; ++i) {
    int linear = tid * 8 + i * 2048;
    int d = linear >> 6, nc = linear & 63;
    u16x8 val;
#pragma unroll
    for (int j = 0; j < 8; ++j) val[j] = lds[nc + j][d];
    *(u16x8*)(dst + (size_t)d * SEQ + nc) = val;
  }
}

// ---------------- flash attention ----------------
// grid (N/64, B*H); 4 waves; wave w handles 16 q rows. q pre-scaled by ATT_SCALE.
__global__ __launch_bounds__(256) void flash_attn(const u16* __restrict__ q, const u16* __restrict__ k,
                                                  const u16* __restrict__ vt, const float* __restrict__ maskf,
                                                  u16* __restrict__ attnout) {
  __shared__ __align__(16) char lds[24576];   // K 8K | Vt 8K | P 4x2K
  const int tid = threadIdx.x;
  const int lane = tid & 63, wid = tid >> 6;
  const int bh = blockIdx.y;
  const int q0 = blockIdx.x * 64;
  const int b = bh >> 4, h = bh & 15;
  const size_t headoff = (size_t)bh * (SEQ * HDIM);

  short8 aq[2];
  {
    const u16* qp = q + headoff + (size_t)(q0 + wid * 16 + (lane & 15)) * HDIM + ((lane >> 4) << 3);
    aq[0] = *(const short8*)qp;
    aq[1] = *(const short8*)(qp + 32);
  }
  float mrun[4] = {-1e30f, -1e30f, -1e30f, -1e30f};
  float lsum[4] = {0.f, 0.f, 0.f, 0.f};
  f32x4 oacc[4] = {};

  char* Ks = lds;
  char* Vs = lds + 8192;
  char* Ps = lds + 16384 + wid * 2048;
  const float* mrow = maskf + b * SEQ;

  for (int kv0 = 0; kv0 < SEQ; kv0 += 64) {
#pragma unroll
    for (int c = 0; c < 2; ++c) {
      const int o = c * 4096 + wid * 1024 + (lane << 4);
      const int row = o >> 7;
      const int colb = (o & 127) ^ ((row & 7) << 4);
      gload_lds16((const char*)(k + headoff + (size_t)(kv0 + row) * HDIM) + colb, Ks + c * 4096 + wid * 1024);
      gload_lds16((const char*)(vt + headoff + (size_t)row * SEQ + kv0) + colb, Vs + c * 4096 + wid * 1024);
    }
    __syncthreads();

    f32x4 s[4] = {};
#pragma unroll
    for (int ks = 0; ks < 2; ++ks)
#pragma unroll
      for (int n = 0; n < 4; ++n) {
        const int krow = n * 16 + (lane & 15);
        const int koff = (ks * 64 + ((lane >> 4) << 4)) ^ ((krow & 7) << 4);
        short8 bk = *(const short8*)(Ks + (krow << 7) + koff);
        s[n] = __builtin_amdgcn_mfma_f32_16x16x32_bf16(aq[ks], bk, s[n], 0, 0, 0);
      }

    float mk[4];
#pragma unroll
    for (int n = 0; n < 4; ++n) mk[n] = mrow[kv0 + n * 16 + (lane & 15)];

    float alpha[4];
#pragma unroll
    for (int r = 0; r < 4; ++r) {
      float s0 = s[0][r] + mk[0], s1 = s[1][r] + mk[1];
      float s2 = s[2][r] + mk[2], s3 = s[3][r] + mk[3];
      float mx = fmaxf(fmaxf(s0, s1), fmaxf(s2, s3));
      mx = fmaxf(mx, __shfl_xor(mx, 1));
      mx = fmaxf(mx, __shfl_xor(mx, 2));
      mx = fmaxf(mx, __shfl_xor(mx, 4));
      mx = fmaxf(mx, __shfl_xor(mx, 8));
      const float mn = fmaxf(mrun[r], mx);
      alpha[r] = __expf(mrun[r] - mn);
      mrun[r] = mn;
      float p0 = __expf(s0 - mn), p1 = __expf(s1 - mn);
      float p2 = __expf(s2 - mn), p3 = __expf(s3 - mn);
      s[0][r] = p0; s[1][r] = p1; s[2][r] = p2; s[3][r] = p3;
      float rsum = (p0 + p1) + (p2 + p3);
      rsum += __shfl_xor(rsum, 1);
      rsum += __shfl_xor(rsum, 2);
      rsum += __shfl_xor(rsum, 4);
      rsum += __shfl_xor(rsum, 8);
      lsum[r] = lsum[r] * alpha[r] + rsum;
    }
    // P -> per-wave LDS (swizzled), bf16
#pragma unroll
    for (int r = 0; r < 4; ++r) {
      const int prow = ((lane >> 4) << 2) + r;
      const int pxor = (prow & 7) << 4;
#pragma unroll
      for (int n = 0; n < 4; ++n) {
        const int off = (prow << 7) + ((n * 32 + ((lane & 15) << 1)) ^ pxor);
        *(u16*)(Ps + off) = f2bf(s[n][r]);
      }
    }
#pragma unroll
    for (int nd = 0; nd < 4; ++nd) {
      oacc[nd][0] *= alpha[0]; oacc[nd][1] *= alpha[1];
      oacc[nd][2] *= alpha[2]; oacc[nd][3] *= alpha[3];
    }
    // O += P @ V
#pragma unroll
    for (int ks = 0; ks < 2; ++ks) {
      const int prow = lane & 15;
      const int poff = (prow << 7) + ((ks * 64 + ((lane >> 4) << 4)) ^ ((prow & 7) << 4));
      short8 ap = *(const short8*)(Ps + poff);
#pragma unroll
      for (int nd = 0; nd < 4; ++nd) {
        const int vrow = nd * 16 + (lane & 15);
        const int voff = (ks * 64 + ((lane >> 4) << 4)) ^ ((vrow & 7) << 4);
        short8 bv = *(const short8*)(Vs + (vrow << 7) + voff);
        oacc[nd] = __builtin_amdgcn_mfma_f32_16x16x32_bf16(ap, bv, oacc[nd], 0, 0, 0);
      }
    }
    __syncthreads();
  }

  float inv[4];
#pragma unroll
  for (int r = 0; r < 4; ++r) inv[r] = 1.0f / lsum[r];
  u16* outp = attnout + (size_t)(b * SEQ + q0 + wid * 16) * MODELD + h * HDIM;
#pragma unroll
  for (int nd = 0; nd < 4; ++nd)
#pragma unroll
    for (int r = 0; r < 4; ++r) {
      const int row = ((lane >> 4) << 2) + r;
      outp[(size_t)row * MODELD + nd * 16 + (lane & 15)] = f2bf(oacc[nd][r] * inv[r]);
    }
}

// ---------------- launch ----------------
extern "C" void kernel_launch(void* const* d_in, const int* in_sizes, int n_in,
                              void* d_out, int out_size, void* d_ws, size_t ws_size,
                              hipStream_t stream) {
  const float* x       = (const float*)d_in[0];
  const unsigned int* mask = (const unsigned int*)d_in[1];
  const float* w_qkv   = (const float*)d_in[2];
  const float* wq_base = (const float*)d_in[3];
  const float* bq      = (const float*)d_in[4];
  const float* wq_A    = (const float*)d_in[5];
  const float* wq_B    = (const float*)d_in[6];
  const float* wv_base = (const float*)d_in[7];
  const float* bv      = (const float*)d_in[8];
  const float* wv_A    = (const float*)d_in[9];
  const float* wv_B    = (const float*)d_in[10];
  const float* w_out   = (const float*)d_in[11];
  const float* b_out   = (const float*)d_in[12];
  float* out = (float*)d_out;

  char* ws = (char*)d_ws;
  u16* xb      = (u16*)(ws);                 // 8 MB  (reused as attnout)
  u16* wcomb   = (u16*)(ws + 8388608);       // 6 MB
  u16* woutb   = (u16*)(ws + 14680064);      // 2 MB
  u16* qws     = (u16*)(ws + 16777216);      // 8 MB
  u16* kws     = (u16*)(ws + 25165824);      // 8 MB
  u16* vws     = (u16*)(ws + 33554432);      // 8 MB
  u16* vtws    = (u16*)(ws + 41943040);      // 8 MB
  float* biasc = (float*)(ws + 50331648);    // 12 KB
  float* maskf = (float*)(ws + 50343936);    // 16 KB
  u16* attnout = xb;                          // xb dead after gemm_qkv

  prep_cast<<<4096, 256, 0, stream>>>(x, xb);          // 4M elems
  prep_cast<<<1024, 256, 0, stream>>>(w_out, woutb);   // 1M elems
  prep_mask<<<1, 256, 0, stream>>>(mask, maskf);
  prep_w<<<3072, 256, 0, stream>>>(w_qkv, wq_base, bq, wq_A, wq_B,
                                   wv_base, bv, wv_A, wv_B, wcomb, biasc);

  gemm128<0><<<dim3(QKVCOLS / 128, MROWS / 128), 256, 0, stream>>>(
      xb, wcomb, biasc, qws, kws, vws, nullptr);

  transpose_v<<<dim3(SEQ / 64, 32), 256, 0, stream>>>(vws, vtws);

  flash_attn<<<dim3(SEQ / 64, 32), 256, 0, stream>>>(qws, kws, vtws, maskf, attnout);

  gemm128<1><<<dim3(MODELD / 128, MROWS / 128), 256, 0, stream>>>(
      attnout, woutb, b_out, nullptr, nullptr, nullptr, out);
}

// Round 4
// 207.354 us; speedup vs baseline: 1.2054x; 1.2005x over previous
//
#include <hip/hip_runtime.h>

typedef unsigned short u16;
typedef unsigned int u32;
typedef __attribute__((ext_vector_type(2))) unsigned int u32x2;
typedef __attribute__((ext_vector_type(4))) unsigned short u16x4;
typedef __attribute__((ext_vector_type(8))) unsigned short u16x8;
typedef __attribute__((ext_vector_type(8))) short short8;
typedef __attribute__((ext_vector_type(4))) float f32x4;

#define NHEAD 16
#define HDIM 64
#define SEQ 2048
#define MODELD 1024
#define MROWS 4096            // B*N
#define QKVCOLS 3072
// ATT_SCALE * log2(e), folded into q weights/bias so softmax uses exp2
#define QSCALE 0.18033688011112042f

__device__ __forceinline__ u16 f2bf(float f) {
  union { float f; unsigned u; } v; v.f = f;
  unsigned r = v.u + 0x7FFFu + ((v.u >> 16) & 1u);
  return (u16)(r >> 16);
}

__device__ __forceinline__ void gload_lds16(const void* g, void* l) {
  __builtin_amdgcn_global_load_lds((const __attribute__((address_space(1))) void*)g,
                                   (__attribute__((address_space(3))) void*)l, 16, 0, 0);
}

// ---------------- prep kernels ----------------

// f32 -> bf16, 4 elems/thread, exact grid
__global__ void prep_cast(const float* __restrict__ in, u16* __restrict__ outb) {
  int i = blockIdx.x * 256 + threadIdx.x;
  float4 v = *(const float4*)(in + (size_t)i * 4);
  u16x4 o = {f2bf(v.x), f2bf(v.y), f2bf(v.z), f2bf(v.w)};
  *(u16x4*)(outb + (size_t)i * 4) = o;
}

// mask -> additive float; auto-detect int32 vs byte(bool) marshalling
__global__ void prep_mask(const unsigned int* __restrict__ mraw, float* __restrict__ mf) {
  __shared__ int is_bytes;
  if (threadIdx.x == 0) {
    int bytes = 0;
    for (int i = 0; i < 1024; ++i) { if (mraw[i] > 1u) { bytes = 1; break; } }
    is_bytes = bytes;
  }
  __syncthreads();
  const unsigned char* bp = (const unsigned char*)mraw;
  for (int i = threadIdx.x; i < 2 * SEQ; i += 256) {
    unsigned val = is_bytes ? (unsigned)bp[i] : mraw[i];
    mf[i] = val ? 0.f : -1e30f;
  }
}

// combined qkv weight (bf16) with LoRA + base fold; q rows pre-scaled by ATT_SCALE*log2e
__global__ void prep_w(const float* __restrict__ wqkv,
                       const float* __restrict__ wqb, const float* __restrict__ bq,
                       const float* __restrict__ wqA, const float* __restrict__ wqB,
                       const float* __restrict__ wvb, const float* __restrict__ bv,
                       const float* __restrict__ wvA, const float* __restrict__ wvB,
                       u16* __restrict__ wcomb, float* __restrict__ biasc) {
  const int c = blockIdx.x;             // 0..3071
  const int t = c >> 10, hd = c & 1023;
  const int k0 = threadIdx.x * 4;
  float4 w = *(const float4*)(wqkv + (size_t)c * MODELD + k0);
  float a0 = w.x, a1 = w.y, a2 = w.z, a3 = w.w;
  if (t != 1) {
    const float* base = (t == 0 ? wqb : wvb) + (size_t)hd * MODELD + k0;
    const float* A = (t == 0 ? wqA : wvA);
    const float* Bm = (t == 0 ? wqB : wvB) + hd * 10;
    float4 bsv = *(const float4*)base;
    a0 += bsv.x; a1 += bsv.y; a2 += bsv.z; a3 += bsv.w;
#pragma unroll
    for (int j = 0; j < 10; ++j) {
      float bj = Bm[j] * 0.1f;               // LORA_SCALE = 1/R
      float4 av = *(const float4*)(A + (size_t)j * MODELD + k0);
      a0 += bj * av.x; a1 += bj * av.y; a2 += bj * av.z; a3 += bj * av.w;
    }
    if (t == 0) { a0 *= QSCALE; a1 *= QSCALE; a2 *= QSCALE; a3 *= QSCALE; }
  }
  u16x4 o = {f2bf(a0), f2bf(a1), f2bf(a2), f2bf(a3)};
  *(u16x4*)(wcomb + (size_t)c * MODELD + k0) = o;
  if (threadIdx.x == 0)
    biasc[c] = (t == 0) ? QSCALE * bq[hd] : ((t == 2) ? bv[hd] : 0.f);
}

// ---------------- 128x128 bf16 MFMA GEMM, BK=64, swizzled LDS ----------------
// C = A(bf16,[M][1024]) @ W(bf16,[Ncols][1024])^T ; MODE 0: scatter q/k/v, MODE 1: f32 + bias
template<int MODE>
__global__ __launch_bounds__(256) void gemm128(const u16* __restrict__ A, const u16* __restrict__ W,
                                               const float* __restrict__ bias,
                                               u16* __restrict__ oq, u16* __restrict__ ok, u16* __restrict__ ov,
                                               float* __restrict__ of) {
  __shared__ __align__(16) char lds[32768];
  const int tid = threadIdx.x;
  const int lane = tid & 63;
  const int wid = tid >> 6;
  const int wr = wid >> 1, wc = wid & 1;
  const int m0 = blockIdx.y << 7;
  const int n0 = blockIdx.x << 7;
  const int K = MODELD;

  f32x4 acc[4][4] = {};

  const int so = wid * 1024 + (lane << 4);
  for (int kt = 0; kt < K; kt += 64) {
#pragma unroll
    for (int c = 0; c < 4; ++c) {
      const int o = c * 4096 + so;
      const int row = o >> 7;
      const int colb = (o & 127) ^ ((row & 7) << 4);   // inverse-swizzled global source (m173)
      gload_lds16((const char*)(A + (size_t)(m0 + row) * K + kt) + colb, lds + (c * 4096 + wid * 1024));
      gload_lds16((const char*)(W + (size_t)(n0 + row) * K + kt) + colb, lds + (16384 + c * 4096 + wid * 1024));
    }
    __syncthreads();
#pragma unroll
    for (int ks = 0; ks < 2; ++ks) {
      short8 av[4], bv[4];
#pragma unroll
      for (int i = 0; i < 4; ++i) {
        const int arow = wr * 64 + i * 16 + (lane & 15);
        const int off = (ks * 64 + ((lane >> 4) << 4)) ^ ((lane & 7) << 4); // (row&7)==(lane&7)
        av[i] = *(const short8*)(lds + (arow << 7) + off);
        const int brow = wc * 64 + i * 16 + (lane & 15);
        bv[i] = *(const short8*)(lds + 16384 + (brow << 7) + off);
      }
#pragma unroll
      for (int i = 0; i < 4; ++i)
#pragma unroll
        for (int j = 0; j < 4; ++j)
          acc[i][j] = __builtin_amdgcn_mfma_f32_16x16x32_bf16(av[i], bv[j], acc[i][j], 0, 0, 0);
    }
    __syncthreads();
  }

  if (MODE == 0) {
#pragma unroll
    for (int j = 0; j < 4; ++j) {
      const int col = n0 + wc * 64 + j * 16 + (lane & 15);
      const int t = col >> 10;
      const int hd = col & 1023;
      const int h = hd >> 6, d = hd & 63;
      const float bs = bias[col];
      u16* dst = (t == 0) ? oq : ((t == 1) ? ok : ov);
#pragma unroll
      for (int i = 0; i < 4; ++i) {
        const int rowb = m0 + wr * 64 + i * 16 + ((lane >> 4) << 2);
#pragma unroll
        for (int r = 0; r < 4; ++r) {
          const int row = rowb + r;
          const int b = row >> 11, n = row & 2047;
          dst[((size_t)(b * NHEAD + h) * SEQ + n) * HDIM + d] = f2bf(acc[i][j][r] + bs);
        }
      }
    }
  } else {
#pragma unroll
    for (int j = 0; j < 4; ++j) {
      const int col = n0 + wc * 64 + j * 16 + (lane & 15);
      const float bs = bias[col];
#pragma unroll
      for (int i = 0; i < 4; ++i) {
        const int rowb = m0 + wr * 64 + i * 16 + ((lane >> 4) << 2);
#pragma unroll
        for (int r = 0; r < 4; ++r)
          of[(size_t)(rowb + r) * MODELD + col] = acc[i][j][r] + bs;
      }
    }
  }
}

// ---------------- V transpose: [bh][n][d] -> [bh][d][n] ----------------
__global__ void transpose_v(const u16* __restrict__ v, u16* __restrict__ vt) {
  __shared__ u16 lds[64][72];
  const int bh = blockIdx.y, n0 = blockIdx.x * 64;
  const int tid = threadIdx.x;
  const u16* src = v + (size_t)bh * SEQ * HDIM + (size_t)n0 * HDIM;
#pragma unroll
  for (int i = 0; i < 2; ++i) {
    int linear = tid * 8 + i * 2048;
    int row = linear >> 6, col = linear & 63;
    *(u16x8*)(&lds[row][col]) = *(const u16x8*)(src + row * 64 + col);
  }
  __syncthreads();
  u16* dst = vt + (size_t)bh * HDIM * SEQ + n0;
#pragma unroll
  for (int i = 0; i < 2; ++i) {
    int linear = tid * 8 + i * 2048;
    int d = linear >> 6, nc = linear & 63;
    u16x8 val;
#pragma unroll
    for (int j = 0; j < 8; ++j) val[j] = lds[nc + j][d];
    *(u16x8*)(dst + (size_t)d * SEQ + nc) = val;
  }
}

// ---------------- flash attention (swapped operands, no-max softmax) ----------------
// 1D grid of 1024 blocks, XCD-pinned: 4 heads per XCD. 4 waves; wave w owns 16 q rows.
// S^T = mfma(K, Q): lane holds P[q=lane&15][kv=16n+4hi+r]. No shuffles in the loop.
__global__ __launch_bounds__(256) void flash_attn(const u16* __restrict__ q, const u16* __restrict__ k,
                                                  const u16* __restrict__ vt, const float* __restrict__ maskf,
                                                  u16* __restrict__ attnout) {
  // LDS: K dbuf 2x8K | Vt dbuf 2x8K | mask 8K | P 4x2K  = 48KB
  __shared__ __align__(16) char lds[49152];
  const int tid = threadIdx.x;
  const int lane = tid & 63, wid = tid >> 6;
  const int qi = lane & 15, hi = lane >> 4;
  const int bid = blockIdx.x;
  const int bh = (bid & 7) * 4 + ((bid >> 3) >> 5);   // XCD-pinned: head group = dispatch%8
  const int q0 = ((bid >> 3) & 31) * 64;
  const int b = bh >> 4, h = bh & 15;
  const size_t headoff = (size_t)bh * (SEQ * HDIM);

  // Q registers (B-operand fragment: col=q, k=(hi*8..))
  short8 aq[2];
  {
    const u16* qp = q + headoff + (size_t)(q0 + wid * 16 + qi) * HDIM + hi * 8;
    aq[0] = *(const short8*)qp;
    aq[1] = *(const short8*)(qp + 32);
  }

  float* mL = (float*)(lds + 32768);
  char* Pw = lds + 40960 + wid * 2048;

  // stage mask (2048 f32 = 8KB), once
  {
    const float4* msrc = (const float4*)(maskf + b * SEQ);
    float4* mdst = (float4*)mL;
    mdst[tid] = msrc[tid];
    mdst[tid + 256] = msrc[tid + 256];
  }

  const int so = wid * 1024 + (lane << 4);
  auto stage = [&](int buf, int kv0) {
    char* kb = lds + buf * 8192;
    char* vb = lds + 16384 + buf * 8192;
#pragma unroll
    for (int c = 0; c < 2; ++c) {
      const int o = c * 4096 + so;
      const int row = o >> 7;
      const int colb = (o & 127) ^ ((row & 7) << 4);
      gload_lds16((const char*)(k + headoff + (size_t)(kv0 + row) * HDIM) + colb, kb + c * 4096 + wid * 1024);
      gload_lds16((const char*)(vt + headoff + (size_t)row * SEQ + kv0) + colb, vb + c * 4096 + wid * 1024);
    }
  };
  stage(0, 0);
  __syncthreads();

  f32x4 oacc[4] = {};
  f32x4 psum = {0.f, 0.f, 0.f, 0.f};
  const int pxor = (qi & 7) << 4;   // (row&7)<<4 for all K/Vt/P rows used by this lane

  for (int t = 0; t < 32; ++t) {
    const int cur = t & 1;
    if (t < 31) stage(cur ^ 1, (t + 1) * 64);   // prefetch overlaps compute (T3-min)

    char* kb = lds + cur * 8192;
    char* vb = lds + 16384 + cur * 8192;

    // QK^T swapped: s[n][r] = S[q][kv=64t+16n+4hi+r]
    f32x4 s[4] = {};
#pragma unroll
    for (int ks = 0; ks < 2; ++ks) {
      const int off = (ks * 64 + (hi << 4)) ^ pxor;
#pragma unroll
      for (int n = 0; n < 4; ++n) {
        short8 ak = *(const short8*)(kb + ((n * 16 + qi) << 7) + off);
        s[n] = __builtin_amdgcn_mfma_f32_16x16x32_bf16(ak, aq[ks], s[n], 0, 0, 0);
      }
    }

    // softmax, no max-tracking: P = exp2(s + mask); lane-local psum
    const float* mrow = mL + t * 64 + hi * 4;
#pragma unroll
    for (int n = 0; n < 4; ++n) {
      f32x4 mk = *(const f32x4*)(mrow + n * 16);
      float e0 = exp2f(s[n][0] + mk[0]);
      float e1 = exp2f(s[n][1] + mk[1]);
      float e2 = exp2f(s[n][2] + mk[2]);
      float e3 = exp2f(s[n][3] + mk[3]);
      psum[0] += e0; psum[1] += e1; psum[2] += e2; psum[3] += e3;
      u32x2 pkw;
      pkw[0] = (u32)f2bf(e0) | ((u32)f2bf(e1) << 16);
      pkw[1] = (u32)f2bf(e2) | ((u32)f2bf(e3) << 16);
      *(u32x2*)(Pw + (qi << 7) + ((32 * n + 8 * hi) ^ pxor)) = pkw;   // per-wave buffer, in-wave lgkmcnt only
    }

    // PV swapped: O^T[d][q] += Vt · P^T
#pragma unroll
    for (int ks = 0; ks < 2; ++ks) {
      const int off = (ks * 64 + (hi << 4)) ^ pxor;
      short8 ap = *(const short8*)(Pw + (qi << 7) + off);
#pragma unroll
      for (int nd = 0; nd < 4; ++nd) {
        short8 av = *(const short8*)(vb + ((nd * 16 + qi) << 7) + off);
        oacc[nd] = __builtin_amdgcn_mfma_f32_16x16x32_bf16(av, ap, oacc[nd], 0, 0, 0);
      }
    }
    __syncthreads();   // releases buf[cur] for overwrite AND drains prefetch vmcnt
  }

  // lsum: lane-local horizontal + 2 shuffles (lanes sharing q)
  float l = (psum[0] + psum[1]) + (psum[2] + psum[3]);
  l += __shfl_xor(l, 16);
  l += __shfl_xor(l, 32);
  const float inv = 1.0f / l;

  // O^T: lane holds O[q][d = nd*16 + 4hi + r]
  u16* outp = attnout + (size_t)(b * SEQ + q0 + wid * 16 + qi) * MODELD + h * HDIM;
#pragma unroll
  for (int nd = 0; nd < 4; ++nd) {
    u16x4 o4;
#pragma unroll
    for (int r = 0; r < 4; ++r) o4[r] = f2bf(oacc[nd][r] * inv);
    *(u16x4*)(outp + nd * 16 + hi * 4) = o4;
  }
}

// ---------------- launch ----------------
extern "C" void kernel_launch(void* const* d_in, const int* in_sizes, int n_in,
                              void* d_out, int out_size, void* d_ws, size_t ws_size,
                              hipStream_t stream) {
  const float* x       = (const float*)d_in[0];
  const unsigned int* mask = (const unsigned int*)d_in[1];
  const float* w_qkv   = (const float*)d_in[2];
  const float* wq_base = (const float*)d_in[3];
  const float* bq      = (const float*)d_in[4];
  const float* wq_A    = (const float*)d_in[5];
  const float* wq_B    = (const float*)d_in[6];
  const float* wv_base = (const float*)d_in[7];
  const float* bv      = (const float*)d_in[8];
  const float* wv_A    = (const float*)d_in[9];
  const float* wv_B    = (const float*)d_in[10];
  const float* w_out   = (const float*)d_in[11];
  const float* b_out   = (const float*)d_in[12];
  float* out = (float*)d_out;

  char* ws = (char*)d_ws;
  u16* xb      = (u16*)(ws);                 // 8 MB  (reused as attnout)
  u16* wcomb   = (u16*)(ws + 8388608);       // 6 MB
  u16* woutb   = (u16*)(ws + 14680064);      // 2 MB
  u16* qws     = (u16*)(ws + 16777216);      // 8 MB
  u16* kws     = (u16*)(ws + 25165824);      // 8 MB
  u16* vws     = (u16*)(ws + 33554432);      // 8 MB
  u16* vtws    = (u16*)(ws + 41943040);      // 8 MB
  float* biasc = (float*)(ws + 50331648);    // 12 KB
  float* maskf = (float*)(ws + 50343936);    // 16 KB
  u16* attnout = xb;                          // xb dead after gemm_qkv

  prep_cast<<<4096, 256, 0, stream>>>(x, xb);          // 4M elems
  prep_cast<<<1024, 256, 0, stream>>>(w_out, woutb);   // 1M elems
  prep_mask<<<1, 256, 0, stream>>>(mask, maskf);
  prep_w<<<3072, 256, 0, stream>>>(w_qkv, wq_base, bq, wq_A, wq_B,
                                   wv_base, bv, wv_A, wv_B, wcomb, biasc);

  gemm128<0><<<dim3(QKVCOLS / 128, MROWS / 128), 256, 0, stream>>>(
      xb, wcomb, biasc, qws, kws, vws, nullptr);

  transpose_v<<<dim3(SEQ / 64, 32), 256, 0, stream>>>(vws, vtws);

  flash_attn<<<1024, 256, 0, stream>>>(qws, kws, vtws, maskf, attnout);

  gemm128<1><<<dim3(MODELD / 128, MROWS / 128), 256, 0, stream>>>(
      attnout, woutb, b_out, nullptr, nullptr, nullptr, out);
}

// Round 5
// 206.318 us; speedup vs baseline: 1.2115x; 1.0050x over previous
//
#include <hip/hip_runtime.h>

typedef unsigned short u16;
typedef unsigned int u32;
typedef __attribute__((ext_vector_type(2))) unsigned int u32x2;
typedef __attribute__((ext_vector_type(4))) unsigned short u16x4;
typedef __attribute__((ext_vector_type(8))) unsigned short u16x8;
typedef __attribute__((ext_vector_type(8))) short short8;
typedef __attribute__((ext_vector_type(4))) float f32x4;

#define NHEAD 16
#define HDIM 64
#define SEQ 2048
#define MODELD 1024
#define MROWS 4096            // B*N
#define QKVCOLS 3072
// ATT_SCALE * log2(e), folded into q weights/bias so softmax uses exp2
#define QSCALE 0.18033688011112042f

__device__ __forceinline__ u16 f2bf(float f) {
  union { float f; unsigned u; } v; v.f = f;
  unsigned r = v.u + 0x7FFFu + ((v.u >> 16) & 1u);
  return (u16)(r >> 16);
}

// packed f32x2 -> bf16x2 (RTNE), single instruction (T12; no builtin on gfx950)
__device__ __forceinline__ u32 cvtpk(float lo, float hi) {
  u32 r;
  asm("v_cvt_pk_bf16_f32 %0, %1, %2" : "=v"(r) : "v"(lo), "v"(hi));
  return r;
}

__device__ __forceinline__ void gload_lds16(const void* g, void* l) {
  __builtin_amdgcn_global_load_lds((const __attribute__((address_space(1))) void*)g,
                                   (__attribute__((address_space(3))) void*)l, 16, 0, 0);
}

// ---------------- prep kernels ----------------

// f32 -> bf16, 4 elems/thread, exact grid
__global__ void prep_cast(const float* __restrict__ in, u16* __restrict__ outb) {
  int i = blockIdx.x * 256 + threadIdx.x;
  float4 v = *(const float4*)(in + (size_t)i * 4);
  u16x4 o = {f2bf(v.x), f2bf(v.y), f2bf(v.z), f2bf(v.w)};
  *(u16x4*)(outb + (size_t)i * 4) = o;
}

// mask -> additive float; auto-detect int32 vs byte(bool) marshalling
__global__ void prep_mask(const unsigned int* __restrict__ mraw, float* __restrict__ mf) {
  __shared__ int is_bytes;
  if (threadIdx.x == 0) {
    int bytes = 0;
    for (int i = 0; i < 1024; ++i) { if (mraw[i] > 1u) { bytes = 1; break; } }
    is_bytes = bytes;
  }
  __syncthreads();
  const unsigned char* bp = (const unsigned char*)mraw;
  for (int i = threadIdx.x; i < 2 * SEQ; i += 256) {
    unsigned val = is_bytes ? (unsigned)bp[i] : mraw[i];
    mf[i] = val ? 0.f : -1e30f;
  }
}

// combined qkv weight (bf16) with LoRA + base fold; q rows pre-scaled by ATT_SCALE*log2e
__global__ void prep_w(const float* __restrict__ wqkv,
                       const float* __restrict__ wqb, const float* __restrict__ bq,
                       const float* __restrict__ wqA, const float* __restrict__ wqB,
                       const float* __restrict__ wvb, const float* __restrict__ bv,
                       const float* __restrict__ wvA, const float* __restrict__ wvB,
                       u16* __restrict__ wcomb, float* __restrict__ biasc) {
  const int c = blockIdx.x;             // 0..3071
  const int t = c >> 10, hd = c & 1023;
  const int k0 = threadIdx.x * 4;
  float4 w = *(const float4*)(wqkv + (size_t)c * MODELD + k0);
  float a0 = w.x, a1 = w.y, a2 = w.z, a3 = w.w;
  if (t != 1) {
    const float* base = (t == 0 ? wqb : wvb) + (size_t)hd * MODELD + k0;
    const float* A = (t == 0 ? wqA : wvA);
    const float* Bm = (t == 0 ? wqB : wvB) + hd * 10;
    float4 bsv = *(const float4*)base;
    a0 += bsv.x; a1 += bsv.y; a2 += bsv.z; a3 += bsv.w;
#pragma unroll
    for (int j = 0; j < 10; ++j) {
      float bj = Bm[j] * 0.1f;               // LORA_SCALE = 1/R
      float4 av = *(const float4*)(A + (size_t)j * MODELD + k0);
      a0 += bj * av.x; a1 += bj * av.y; a2 += bj * av.z; a3 += bj * av.w;
    }
    if (t == 0) { a0 *= QSCALE; a1 *= QSCALE; a2 *= QSCALE; a3 *= QSCALE; }
  }
  u16x4 o = {f2bf(a0), f2bf(a1), f2bf(a2), f2bf(a3)};
  *(u16x4*)(wcomb + (size_t)c * MODELD + k0) = o;
  if (threadIdx.x == 0)
    biasc[c] = (t == 0) ? QSCALE * bq[hd] : ((t == 2) ? bv[hd] : 0.f);
}

// ---------------- 128x128 bf16 MFMA GEMM, BK=64, swizzled LDS ----------------
// C = A(bf16,[M][1024]) @ W(bf16,[Ncols][1024])^T ; MODE 0: scatter q/k/v, MODE 1: f32 + bias
template<int MODE>
__global__ __launch_bounds__(256) void gemm128(const u16* __restrict__ A, const u16* __restrict__ W,
                                               const float* __restrict__ bias,
                                               u16* __restrict__ oq, u16* __restrict__ ok, u16* __restrict__ ov,
                                               float* __restrict__ of) {
  __shared__ __align__(16) char lds[32768];
  const int tid = threadIdx.x;
  const int lane = tid & 63;
  const int wid = tid >> 6;
  const int wr = wid >> 1, wc = wid & 1;
  const int m0 = blockIdx.y << 7;
  const int n0 = blockIdx.x << 7;
  const int K = MODELD;

  f32x4 acc[4][4] = {};

  const int so = wid * 1024 + (lane << 4);
  for (int kt = 0; kt < K; kt += 64) {
#pragma unroll
    for (int c = 0; c < 4; ++c) {
      const int o = c * 4096 + so;
      const int row = o >> 7;
      const int colb = (o & 127) ^ ((row & 7) << 4);   // inverse-swizzled global source (m173)
      gload_lds16((const char*)(A + (size_t)(m0 + row) * K + kt) + colb, lds + (c * 4096 + wid * 1024));
      gload_lds16((const char*)(W + (size_t)(n0 + row) * K + kt) + colb, lds + (16384 + c * 4096 + wid * 1024));
    }
    __syncthreads();
#pragma unroll
    for (int ks = 0; ks < 2; ++ks) {
      short8 av[4], bv[4];
#pragma unroll
      for (int i = 0; i < 4; ++i) {
        const int arow = wr * 64 + i * 16 + (lane & 15);
        const int off = (ks * 64 + ((lane >> 4) << 4)) ^ ((lane & 7) << 4); // (row&7)==(lane&7)
        av[i] = *(const short8*)(lds + (arow << 7) + off);
        const int brow = wc * 64 + i * 16 + (lane & 15);
        bv[i] = *(const short8*)(lds + 16384 + (brow << 7) + off);
      }
#pragma unroll
      for (int i = 0; i < 4; ++i)
#pragma unroll
        for (int j = 0; j < 4; ++j)
          acc[i][j] = __builtin_amdgcn_mfma_f32_16x16x32_bf16(av[i], bv[j], acc[i][j], 0, 0, 0);
    }
    __syncthreads();
  }

  if (MODE == 0) {
#pragma unroll
    for (int j = 0; j < 4; ++j) {
      const int col = n0 + wc * 64 + j * 16 + (lane & 15);
      const int t = col >> 10;
      const int hd = col & 1023;
      const int h = hd >> 6, d = hd & 63;
      const float bs = bias[col];
      u16* dst = (t == 0) ? oq : ((t == 1) ? ok : ov);
#pragma unroll
      for (int i = 0; i < 4; ++i) {
        const int rowb = m0 + wr * 64 + i * 16 + ((lane >> 4) << 2);
#pragma unroll
        for (int r = 0; r < 4; ++r) {
          const int row = rowb + r;
          const int b = row >> 11, n = row & 2047;
          dst[((size_t)(b * NHEAD + h) * SEQ + n) * HDIM + d] = f2bf(acc[i][j][r] + bs);
        }
      }
    }
  } else {
#pragma unroll
    for (int j = 0; j < 4; ++j) {
      const int col = n0 + wc * 64 + j * 16 + (lane & 15);
      const float bs = bias[col];
#pragma unroll
      for (int i = 0; i < 4; ++i) {
        const int rowb = m0 + wr * 64 + i * 16 + ((lane >> 4) << 2);
#pragma unroll
        for (int r = 0; r < 4; ++r)
          of[(size_t)(rowb + r) * MODELD + col] = acc[i][j][r] + bs;
      }
    }
  }
}

// ---------------- V transpose: [bh][n][d] -> [bh][d][n] ----------------
__global__ void transpose_v(const u16* __restrict__ v, u16* __restrict__ vt) {
  __shared__ u16 lds[64][72];
  const int bh = blockIdx.y, n0 = blockIdx.x * 64;
  const int tid = threadIdx.x;
  const u16* src = v + (size_t)bh * SEQ * HDIM + (size_t)n0 * HDIM;
#pragma unroll
  for (int i = 0; i < 2; ++i) {
    int linear = tid * 8 + i * 2048;
    int row = linear >> 6, col = linear & 63;
    *(u16x8*)(&lds[row][col]) = *(const u16x8*)(src + row * 64 + col);
  }
  __syncthreads();
  u16* dst = vt + (size_t)bh * HDIM * SEQ + n0;
#pragma unroll
  for (int i = 0; i < 2; ++i) {
    int linear = tid * 8 + i * 2048;
    int d = linear >> 6, nc = linear & 63;
    u16x8 val;
#pragma unroll
    for (int j = 0; j < 8; ++j) val[j] = lds[nc + j][d];
    *(u16x8*)(dst + (size_t)d * SEQ + nc) = val;
  }
}

// ---------------- flash attention (swapped operands, no-max softmax) ----------------
// QBLK=128: 4 waves, each wave owns 32 q rows (two 16-row halves sharing every
// K/V LDS read -> per-q LDS traffic halved). 512 blocks, XCD-pinned 4 heads/XCD.
// S^T = mfma(K, Q): lane holds P[q=lane&15][kv=16n+4hi+r]. No shuffles in the loop.
__global__ __launch_bounds__(256) void flash_attn(const u16* __restrict__ q, const u16* __restrict__ k,
                                                  const u16* __restrict__ vt, const float* __restrict__ maskf,
                                                  u16* __restrict__ attnout) {
  // LDS: K dbuf 2x8K | Vt dbuf 2x8K | mask 8K | P 4x4K  = 56KB
  __shared__ __align__(16) char lds[57344];
  const int tid = threadIdx.x;
  const int lane = tid & 63, wid = tid >> 6;
  const int qi = lane & 15, hi = lane >> 4;
  const int bid = blockIdx.x;
  const int bh = (bid & 7) * 4 + ((bid >> 3) >> 4);   // XCD-pinned: 4 heads per XCD
  const int q0 = ((bid >> 3) & 15) * 128;
  const int b = bh >> 4, h = bh & 15;
  const size_t headoff = (size_t)bh * (SEQ * HDIM);

  // Q registers: two halves (B-operand fragment: col=q, k=(hi*8..))
  short8 aq0[2], aq1[2];
  {
    const u16* qp = q + headoff + (size_t)(q0 + wid * 32 + qi) * HDIM + hi * 8;
    aq0[0] = *(const short8*)qp;
    aq0[1] = *(const short8*)(qp + 32);
    aq1[0] = *(const short8*)(qp + 16 * HDIM);
    aq1[1] = *(const short8*)(qp + 16 * HDIM + 32);
  }

  float* mL = (float*)(lds + 32768);
  char* Pw = lds + 40960 + wid * 4096;

  // stage mask (2048 f32 = 8KB), once
  {
    const float4* msrc = (const float4*)(maskf + b * SEQ);
    float4* mdst = (float4*)mL;
    mdst[tid] = msrc[tid];
    mdst[tid + 256] = msrc[tid + 256];
  }

  const int so = wid * 1024 + (lane << 4);
  auto stage = [&](int buf, int kv0) {
    char* kb = lds + buf * 8192;
    char* vb = lds + 16384 + buf * 8192;
#pragma unroll
    for (int c = 0; c < 2; ++c) {
      const int o = c * 4096 + so;
      const int row = o >> 7;
      const int colb = (o & 127) ^ ((row & 7) << 4);
      gload_lds16((const char*)(k + headoff + (size_t)(kv0 + row) * HDIM) + colb, kb + c * 4096 + wid * 1024);
      gload_lds16((const char*)(vt + headoff + (size_t)row * SEQ + kv0) + colb, vb + c * 4096 + wid * 1024);
    }
  };
  stage(0, 0);
  __syncthreads();

  f32x4 oacc0[4] = {}, oacc1[4] = {};
  f32x4 psum0 = {0.f, 0.f, 0.f, 0.f}, psum1 = {0.f, 0.f, 0.f, 0.f};
  const int pxor = (qi & 7) << 4;   // (row&7)<<4 for all K/Vt/P rows used by this lane

  for (int t = 0; t < 32; ++t) {
    const int cur = t & 1;
    if (t < 31) stage(cur ^ 1, (t + 1) * 64);   // prefetch overlaps compute

    char* kb = lds + cur * 8192;
    char* vb = lds + 16384 + cur * 8192;

    // QK^T swapped, both halves share each K fragment read
    f32x4 s0[4] = {}, s1[4] = {};
    __builtin_amdgcn_s_setprio(1);
#pragma unroll
    for (int ks = 0; ks < 2; ++ks) {
      const int off = (ks * 64 + (hi << 4)) ^ pxor;
#pragma unroll
      for (int n = 0; n < 4; ++n) {
        short8 ak = *(const short8*)(kb + ((n * 16 + qi) << 7) + off);
        s0[n] = __builtin_amdgcn_mfma_f32_16x16x32_bf16(ak, aq0[ks], s0[n], 0, 0, 0);
        s1[n] = __builtin_amdgcn_mfma_f32_16x16x32_bf16(ak, aq1[ks], s1[n], 0, 0, 0);
      }
    }
    __builtin_amdgcn_s_setprio(0);

    // softmax, no max-tracking: P = exp2(s + mask); lane-local psum
    const float* mrow = mL + t * 64 + hi * 4;
#pragma unroll
    for (int half = 0; half < 2; ++half) {
      f32x4* s = half ? s1 : s0;
      f32x4& ps = half ? psum1 : psum0;
      char* Ph = Pw + half * 2048;
#pragma unroll
      for (int n = 0; n < 4; ++n) {
        f32x4 mk = *(const f32x4*)(mrow + n * 16);
        float e0 = exp2f(s[n][0] + mk[0]);
        float e1 = exp2f(s[n][1] + mk[1]);
        float e2 = exp2f(s[n][2] + mk[2]);
        float e3 = exp2f(s[n][3] + mk[3]);
        ps[0] += e0; ps[1] += e1; ps[2] += e2; ps[3] += e3;
        u32x2 pkw;
        pkw[0] = cvtpk(e0, e1);
        pkw[1] = cvtpk(e2, e3);
        *(u32x2*)(Ph + (qi << 7) + ((32 * n + 8 * hi) ^ pxor)) = pkw;
      }
    }

    // PV swapped: O^T[d][q] += Vt . P^T ; each V fragment read feeds both halves
    __builtin_amdgcn_s_setprio(1);
#pragma unroll
    for (int ks = 0; ks < 2; ++ks) {
      const int off = (ks * 64 + (hi << 4)) ^ pxor;
      short8 ap0 = *(const short8*)(Pw + (qi << 7) + off);
      short8 ap1 = *(const short8*)(Pw + 2048 + (qi << 7) + off);
#pragma unroll
      for (int nd = 0; nd < 4; ++nd) {
        short8 av = *(const short8*)(vb + ((nd * 16 + qi) << 7) + off);
        oacc0[nd] = __builtin_amdgcn_mfma_f32_16x16x32_bf16(av, ap0, oacc0[nd], 0, 0, 0);
        oacc1[nd] = __builtin_amdgcn_mfma_f32_16x16x32_bf16(av, ap1, oacc1[nd], 0, 0, 0);
      }
    }
    __builtin_amdgcn_s_setprio(0);
    __syncthreads();   // releases buf[cur] for overwrite AND drains prefetch vmcnt
  }

  // lsum: lane-local horizontal + 2 shuffles (lanes sharing q)
  float l0 = (psum0[0] + psum0[1]) + (psum0[2] + psum0[3]);
  l0 += __shfl_xor(l0, 16);
  l0 += __shfl_xor(l0, 32);
  float l1 = (psum1[0] + psum1[1]) + (psum1[2] + psum1[3]);
  l1 += __shfl_xor(l1, 16);
  l1 += __shfl_xor(l1, 32);
  const float inv0 = 1.0f / l0, inv1 = 1.0f / l1;

  // O^T: lane holds O[q][d = nd*16 + 4hi + r]
  u16* outp = attnout + (size_t)(b * SEQ + q0 + wid * 32 + qi) * MODELD + h * HDIM;
#pragma unroll
  for (int nd = 0; nd < 4; ++nd) {
    u32x2 ow;
    ow[0] = cvtpk(oacc0[nd][0] * inv0, oacc0[nd][1] * inv0);
    ow[1] = cvtpk(oacc0[nd][2] * inv0, oacc0[nd][3] * inv0);
    *(u32x2*)(outp + nd * 16 + hi * 4) = ow;
    u32x2 ow1;
    ow1[0] = cvtpk(oacc1[nd][0] * inv1, oacc1[nd][1] * inv1);
    ow1[1] = cvtpk(oacc1[nd][2] * inv1, oacc1[nd][3] * inv1);
    *(u32x2*)(outp + 16 * MODELD + nd * 16 + hi * 4) = ow1;
  }
}

// ---------------- launch ----------------
extern "C" void kernel_launch(void* const* d_in, const int* in_sizes, int n_in,
                              void* d_out, int out_size, void* d_ws, size_t ws_size,
                              hipStream_t stream) {
  const float* x       = (const float*)d_in[0];
  const unsigned int* mask = (const unsigned int*)d_in[1];
  const float* w_qkv   = (const float*)d_in[2];
  const float* wq_base = (const float*)d_in[3];
  const float* bq      = (const float*)d_in[4];
  const float* wq_A    = (const float*)d_in[5];
  const float* wq_B    = (const float*)d_in[6];
  const float* wv_base = (const float*)d_in[7];
  const float* bv      = (const float*)d_in[8];
  const float* wv_A    = (const float*)d_in[9];
  const float* wv_B    = (const float*)d_in[10];
  const float* w_out   = (const float*)d_in[11];
  const float* b_out   = (const float*)d_in[12];
  float* out = (float*)d_out;

  char* ws = (char*)d_ws;
  u16* xb      = (u16*)(ws);                 // 8 MB  (reused as attnout)
  u16* wcomb   = (u16*)(ws + 8388608);       // 6 MB
  u16* woutb   = (u16*)(ws + 14680064);      // 2 MB
  u16* qws     = (u16*)(ws + 16777216);      // 8 MB
  u16* kws     = (u16*)(ws + 25165824);      // 8 MB
  u16* vws     = (u16*)(ws + 33554432);      // 8 MB
  u16* vtws    = (u16*)(ws + 41943040);      // 8 MB
  float* biasc = (float*)(ws + 50331648);    // 12 KB
  float* maskf = (float*)(ws + 50343936);    // 16 KB
  u16* attnout = xb;                          // xb dead after gemm_qkv

  prep_cast<<<4096, 256, 0, stream>>>(x, xb);          // 4M elems
  prep_cast<<<1024, 256, 0, stream>>>(w_out, woutb);   // 1M elems
  prep_mask<<<1, 256, 0, stream>>>(mask, maskf);
  prep_w<<<3072, 256, 0, stream>>>(w_qkv, wq_base, bq, wq_A, wq_B,
                                   wv_base, bv, wv_A, wv_B, wcomb, biasc);

  gemm128<0><<<dim3(QKVCOLS / 128, MROWS / 128), 256, 0, stream>>>(
      xb, wcomb, biasc, qws, kws, vws, nullptr);

  transpose_v<<<dim3(SEQ / 64, 32), 256, 0, stream>>>(vws, vtws);

  flash_attn<<<512, 256, 0, stream>>>(qws, kws, vtws, maskf, attnout);

  gemm128<1><<<dim3(MODELD / 128, MROWS / 128), 256, 0, stream>>>(
      attnout, woutb, b_out, nullptr, nullptr, nullptr, out);
}

// Round 6
// 149.346 us; speedup vs baseline: 1.6736x; 1.3815x over previous
//
#include <hip/hip_runtime.h>

typedef unsigned short u16;
typedef unsigned int u32;
typedef __attribute__((ext_vector_type(2))) unsigned int u32x2;
typedef __attribute__((ext_vector_type(4))) unsigned short u16x4;
typedef __attribute__((ext_vector_type(8))) unsigned short u16x8;
typedef __attribute__((ext_vector_type(8))) short short8;
typedef __attribute__((ext_vector_type(4))) float f32x4;

#define NHEAD 16
#define HDIM 64
#define SEQ 2048
#define MODELD 1024
#define MROWS 4096            // B*N
#define QKVCOLS 3072
// ATT_SCALE * log2(e), folded into q weights/bias so softmax uses exp2
#define QSCALE 0.18033688011112042f

__device__ __forceinline__ u16 f2bf(float f) {
  union { float f; unsigned u; } v; v.f = f;
  unsigned r = v.u + 0x7FFFu + ((v.u >> 16) & 1u);
  return (u16)(r >> 16);
}

// packed f32x2 -> bf16x2 (RTNE), single instruction (T12; no builtin on gfx950)
__device__ __forceinline__ u32 cvtpk(float lo, float hi) {
  u32 r;
  asm("v_cvt_pk_bf16_f32 %0, %1, %2" : "=v"(r) : "v"(lo), "v"(hi));
  return r;
}

__device__ __forceinline__ void gload_lds16(const void* g, void* l) {
  __builtin_amdgcn_global_load_lds((const __attribute__((address_space(1))) void*)g,
                                   (__attribute__((address_space(3))) void*)l, 16, 0, 0);
}

// ---------------- prep kernels ----------------

// f32 -> bf16, 4 elems/thread, exact grid
__global__ void prep_cast(const float* __restrict__ in, u16* __restrict__ outb) {
  int i = blockIdx.x * 256 + threadIdx.x;
  float4 v = *(const float4*)(in + (size_t)i * 4);
  u16x4 o = {f2bf(v.x), f2bf(v.y), f2bf(v.z), f2bf(v.w)};
  *(u16x4*)(outb + (size_t)i * 4) = o;
}

// mask -> bf16 {1.0, 0.0}; parallel int32-vs-byte marshalling probe.
// 1 block x 1024 threads.
__global__ void prep_mask(const unsigned int* __restrict__ mraw, u16* __restrict__ mbf) {
  __shared__ int flag;
  const int tid = threadIdx.x;
  if (tid == 0) flag = 0;
  __syncthreads();
  // byte-marshalled bools: some of the first 1024 words have a nonzero upper byte
  if (mraw[tid] > 1u) flag = 1;   // race-benign
  __syncthreads();
  const int is_bytes = flag;
  const unsigned char* bp = (const unsigned char*)mraw;
  u16x4 o;
#pragma unroll
  for (int j = 0; j < 4; ++j) {
    unsigned v = is_bytes ? (unsigned)bp[tid * 4 + j] : mraw[tid * 4 + j];
    o[j] = v ? (u16)0x3F80 : (u16)0;   // bf16 1.0 / 0.0
  }
  *(u16x4*)(mbf + tid * 4) = o;
}

// combined qkv weight (bf16) with LoRA + base fold; q rows pre-scaled by ATT_SCALE*log2e
__global__ void prep_w(const float* __restrict__ wqkv,
                       const float* __restrict__ wqb, const float* __restrict__ bq,
                       const float* __restrict__ wqA, const float* __restrict__ wqB,
                       const float* __restrict__ wvb, const float* __restrict__ bv,
                       const float* __restrict__ wvA, const float* __restrict__ wvB,
                       u16* __restrict__ wcomb, float* __restrict__ biasc) {
  const int c = blockIdx.x;             // 0..3071
  const int t = c >> 10, hd = c & 1023;
  const int k0 = threadIdx.x * 4;
  float4 w = *(const float4*)(wqkv + (size_t)c * MODELD + k0);
  float a0 = w.x, a1 = w.y, a2 = w.z, a3 = w.w;
  if (t != 1) {
    const float* base = (t == 0 ? wqb : wvb) + (size_t)hd * MODELD + k0;
    const float* A = (t == 0 ? wqA : wvA);
    const float* Bm = (t == 0 ? wqB : wvB) + hd * 10;
    float4 bsv = *(const float4*)base;
    a0 += bsv.x; a1 += bsv.y; a2 += bsv.z; a3 += bsv.w;
#pragma unroll
    for (int j = 0; j < 10; ++j) {
      float bj = Bm[j] * 0.1f;               // LORA_SCALE = 1/R
      float4 av = *(const float4*)(A + (size_t)j * MODELD + k0);
      a0 += bj * av.x; a1 += bj * av.y; a2 += bj * av.z; a3 += bj * av.w;
    }
    if (t == 0) { a0 *= QSCALE; a1 *= QSCALE; a2 *= QSCALE; a3 *= QSCALE; }
  }
  u16x4 o = {f2bf(a0), f2bf(a1), f2bf(a2), f2bf(a3)};
  *(u16x4*)(wcomb + (size_t)c * MODELD + k0) = o;
  if (threadIdx.x == 0)
    biasc[c] = (t == 0) ? QSCALE * bq[hd] : ((t == 2) ? bv[hd] : 0.f);
}

// ---------------- 128x128 bf16 MFMA GEMM, BK=64, swizzled LDS ----------------
// C = A(bf16,[M][1024]) @ W(bf16,[Ncols][1024])^T ; MODE 0: scatter q/k/v, MODE 1: f32 + bias
template<int MODE>
__global__ __launch_bounds__(256) void gemm128(const u16* __restrict__ A, const u16* __restrict__ W,
                                               const float* __restrict__ bias,
                                               u16* __restrict__ oq, u16* __restrict__ ok, u16* __restrict__ ov,
                                               float* __restrict__ of) {
  __shared__ __align__(16) char lds[32768];
  const int tid = threadIdx.x;
  const int lane = tid & 63;
  const int wid = tid >> 6;
  const int wr = wid >> 1, wc = wid & 1;
  const int m0 = blockIdx.y << 7;
  const int n0 = blockIdx.x << 7;
  const int K = MODELD;

  f32x4 acc[4][4] = {};

  const int so = wid * 1024 + (lane << 4);
  for (int kt = 0; kt < K; kt += 64) {
#pragma unroll
    for (int c = 0; c < 4; ++c) {
      const int o = c * 4096 + so;
      const int row = o >> 7;
      const int colb = (o & 127) ^ ((row & 7) << 4);   // inverse-swizzled global source (m173)
      gload_lds16((const char*)(A + (size_t)(m0 + row) * K + kt) + colb, lds + (c * 4096 + wid * 1024));
      gload_lds16((const char*)(W + (size_t)(n0 + row) * K + kt) + colb, lds + (16384 + c * 4096 + wid * 1024));
    }
    __syncthreads();
#pragma unroll
    for (int ks = 0; ks < 2; ++ks) {
      short8 av[4], bv[4];
#pragma unroll
      for (int i = 0; i < 4; ++i) {
        const int arow = wr * 64 + i * 16 + (lane & 15);
        const int off = (ks * 64 + ((lane >> 4) << 4)) ^ ((lane & 7) << 4); // (row&7)==(lane&7)
        av[i] = *(const short8*)(lds + (arow << 7) + off);
        const int brow = wc * 64 + i * 16 + (lane & 15);
        bv[i] = *(const short8*)(lds + 16384 + (brow << 7) + off);
      }
#pragma unroll
      for (int i = 0; i < 4; ++i)
#pragma unroll
        for (int j = 0; j < 4; ++j)
          acc[i][j] = __builtin_amdgcn_mfma_f32_16x16x32_bf16(av[i], bv[j], acc[i][j], 0, 0, 0);
    }
    __syncthreads();
  }

  if (MODE == 0) {
#pragma unroll
    for (int j = 0; j < 4; ++j) {
      const int col = n0 + wc * 64 + j * 16 + (lane & 15);
      const int t = col >> 10;
      const int hd = col & 1023;
      const int h = hd >> 6, d = hd & 63;
      const float bs = bias[col];
      u16* dst = (t == 0) ? oq : ((t == 1) ? ok : ov);
#pragma unroll
      for (int i = 0; i < 4; ++i) {
        const int rowb = m0 + wr * 64 + i * 16 + ((lane >> 4) << 2);
#pragma unroll
        for (int r = 0; r < 4; ++r) {
          const int row = rowb + r;
          const int b = row >> 11, n = row & 2047;
          dst[((size_t)(b * NHEAD + h) * SEQ + n) * HDIM + d] = f2bf(acc[i][j][r] + bs);
        }
      }
    }
  } else {
#pragma unroll
    for (int j = 0; j < 4; ++j) {
      const int col = n0 + wc * 64 + j * 16 + (lane & 15);
      const float bs = bias[col];
#pragma unroll
      for (int i = 0; i < 4; ++i) {
        const int rowb = m0 + wr * 64 + i * 16 + ((lane >> 4) << 2);
#pragma unroll
        for (int r = 0; r < 4; ++r)
          of[(size_t)(rowb + r) * MODELD + col] = acc[i][j][r] + bs;
      }
    }
  }
}

// ---------------- V transpose: [bh][n][d] -> [bh][d][n], masked columns zeroed ----
__global__ void transpose_v(const u16* __restrict__ v, const u16* __restrict__ mbf,
                            u16* __restrict__ vt) {
  __shared__ u16 lds[64][72];
  const int bh = blockIdx.y, n0 = blockIdx.x * 64;
  const int b = bh >> 4;
  const int tid = threadIdx.x;
  const u16* src = v + (size_t)bh * SEQ * HDIM + (size_t)n0 * HDIM;
#pragma unroll
  for (int i = 0; i < 2; ++i) {
    int linear = tid * 8 + i * 2048;
    int row = linear >> 6, col = linear & 63;
    *(u16x8*)(&lds[row][col]) = *(const u16x8*)(src + row * 64 + col);
  }
  __syncthreads();
  u16* dst = vt + (size_t)bh * HDIM * SEQ + n0;
#pragma unroll
  for (int i = 0; i < 2; ++i) {
    int linear = tid * 8 + i * 2048;
    int d = linear >> 6, nc = linear & 63;
    u16x8 mb = *(const u16x8*)(mbf + b * SEQ + n0 + nc);
    u16x8 val;
#pragma unroll
    for (int j = 0; j < 8; ++j) val[j] = mb[j] ? lds[nc + j][d] : (u16)0;
    *(u16x8*)(dst + (size_t)d * SEQ + nc) = val;
  }
}

// ---------------- flash attention (swapped operands, mask-row lsum, PV pipeline) ----
// 512 blocks XCD-pinned (4 heads/XCD); 4 waves x 32 q-rows (2 halves).
// S^T = mfma(K,Q): lane holds P[q=lane&15][kv]. No mask/psum VALU: Vt row 64 = mask
// (bf16 1/0) so PV's 5th output fragment IS lsum; masked V columns pre-zeroed.
// PV(t-1) is software-pipelined into tile t (V-frags pre-read to regs, P re-read).
__global__ __launch_bounds__(256) void flash_attn(const u16* __restrict__ q, const u16* __restrict__ k,
                                                  const u16* __restrict__ vt, const u16* __restrict__ mbf,
                                                  u16* __restrict__ attnout) {
  // LDS: K dbuf 2x8K @0 | Vt dbuf 2x10K @16384 (80 rows: 64 V + mask + 15 zero) | P 4x4K @36864
  __shared__ __align__(16) char lds[53248];
  const int tid = threadIdx.x;
  const int lane = tid & 63, wid = tid >> 6;
  const int qi = lane & 15, hi = lane >> 4;
  const int bid = blockIdx.x;
  const int bh = (bid & 7) * 4 + (bid >> 7);          // XCD-pinned: 4 heads per XCD
  const int q0 = ((bid >> 3) & 15) * 128;
  const int b = bh >> 4, h = bh & 15;
  const size_t headoff = (size_t)bh * (SEQ * HDIM);

  // Q registers: two 16-row halves (B-operand: col=q, k=hi*8..)
  short8 aq0[2], aq1[2];
  {
    const u16* qp = q + headoff + (size_t)(q0 + wid * 32 + qi) * HDIM + hi * 8;
    aq0[0] = *(const short8*)qp;
    aq0[1] = *(const short8*)(qp + 32);
    aq1[0] = *(const short8*)(qp + 16 * HDIM);
    aq1[1] = *(const short8*)(qp + 16 * HDIM + 32);
  }

  char* Pw = lds + 36864 + wid * 4096;

  // zero Vt rows 65..79 of both buffers once (stage never writes them)
  {
    u32* z0 = (u32*)(lds + 16384 + 65 * 128);
    u32* z1 = (u32*)(lds + 16384 + 10240 + 65 * 128);
    for (int i = tid; i < 480; i += 256) { z0[i] = 0; z1[i] = 0; }
  }

  // strength-reduced staging pointers. row = c*32 + wid*8 + lane/8; row&7 == lane>>3.
  const int srow0 = wid * 8 + (lane >> 3);
  const int colb = (((lane & 7) ^ (lane >> 3)) << 4);     // inverse-swizzled source col
  const char* kg = (const char*)(k + headoff) + srow0 * 128 + colb;
  const char* vg = (const char*)(vt + headoff) + (size_t)srow0 * (SEQ * 2) + colb;
  const char* mg = (const char*)(mbf + b * SEQ) + ((lane & 7) << 4);  // row64: linear (row&7==0)
  char* kl = lds + wid * 1024 + (lane << 4);
  char* vl = lds + 16384 + wid * 1024 + (lane << 4);
  char* ml = lds + 16384 + 8192 + ((lane & 7) << 4);

  auto stage = [&](int buf, int t) {
    const char* ks = kg + (size_t)t * 8192;
    const char* vs = vg + t * 128;
    char* kd = kl + buf * 8192;
    char* vd = vl + buf * 10240;
    gload_lds16(ks, kd);
    gload_lds16(ks + 4096, kd + 4096);
    gload_lds16(vs, vd);
    gload_lds16(vs + (size_t)32 * (SEQ * 2), vd + 4096);
    if (wid == 0 && lane < 8)
      gload_lds16(mg + t * 128, ml + buf * 10240);
  };

  stage(0, 0);
  __syncthreads();

  f32x4 oacc0[5] = {}, oacc1[5] = {};
  short8 av[10];                      // V frags of tile t-1 (read at end of prev iter)
  const int pxor = (qi & 7) << 4;
  const int offk0 = (hi << 4) ^ pxor;
  const int offk1 = (64 + (hi << 4)) ^ pxor;
  const int prow = qi << 7;

  auto pv_prev = [&]() {
    short8 ap00 = *(const short8*)(Pw + prow + offk0);
    short8 ap01 = *(const short8*)(Pw + prow + offk1);
    short8 ap10 = *(const short8*)(Pw + 2048 + prow + offk0);
    short8 ap11 = *(const short8*)(Pw + 2048 + prow + offk1);
    asm volatile("" ::: "memory");   // order P(t-1) reads before P(t) writes below
#pragma unroll
    for (int nd = 0; nd < 5; ++nd) {
      oacc0[nd] = __builtin_amdgcn_mfma_f32_16x16x32_bf16(av[nd], ap00, oacc0[nd], 0, 0, 0);
      oacc0[nd] = __builtin_amdgcn_mfma_f32_16x16x32_bf16(av[5 + nd], ap01, oacc0[nd], 0, 0, 0);
      oacc1[nd] = __builtin_amdgcn_mfma_f32_16x16x32_bf16(av[nd], ap10, oacc1[nd], 0, 0, 0);
      oacc1[nd] = __builtin_amdgcn_mfma_f32_16x16x32_bf16(av[5 + nd], ap11, oacc1[nd], 0, 0, 0);
    }
  };

  for (int t = 0; t < 32; ++t) {
    const int cur = t & 1;
    char* kb = lds + cur * 8192;
    char* vb = lds + 16384 + cur * 10240;
    if (t < 31) stage(cur ^ 1, t + 1);       // prefetch overlaps compute

    __builtin_amdgcn_s_setprio(1);
    if (t > 0) pv_prev();                    // PV(t-1): regs only (av + P LDS)

    // QK(t) swapped: s[n][r] = S[q][kv=64t+16n+4hi+r]
    f32x4 s0[4] = {}, s1[4] = {};
#pragma unroll
    for (int ks = 0; ks < 2; ++ks) {
      const int off = ks ? offk1 : offk0;
#pragma unroll
      for (int n = 0; n < 4; ++n) {
        short8 ak = *(const short8*)(kb + ((n * 16 + qi) << 7) + off);
        s0[n] = __builtin_amdgcn_mfma_f32_16x16x32_bf16(ak, aq0[ks], s0[n], 0, 0, 0);
        s1[n] = __builtin_amdgcn_mfma_f32_16x16x32_bf16(ak, aq1[ks], s1[n], 0, 0, 0);
      }
    }
    __builtin_amdgcn_s_setprio(0);

    // softmax: P = exp2(s) (no mask, no psum -- handled by mask row / zeroed V)
#pragma unroll
    for (int half = 0; half < 2; ++half) {
      f32x4* s = half ? s1 : s0;
      char* Ph = Pw + half * 2048;
#pragma unroll
      for (int n = 0; n < 4; ++n) {
        u32x2 pkw;
        pkw[0] = cvtpk(exp2f(s[n][0]), exp2f(s[n][1]));
        pkw[1] = cvtpk(exp2f(s[n][2]), exp2f(s[n][3]));
        *(u32x2*)(Ph + prow + ((32 * n + 8 * hi) ^ pxor)) = pkw;
      }
    }

    // V(t) fragments -> regs for PV(t) next iter (completes before barrier)
#pragma unroll
    for (int nd = 0; nd < 5; ++nd) {
      av[nd]     = *(const short8*)(vb + ((nd * 16 + qi) << 7) + offk0);
      av[5 + nd] = *(const short8*)(vb + ((nd * 16 + qi) << 7) + offk1);
    }
    __syncthreads();   // releases buf[cur] AND drains prefetch vmcnt/lgkm
  }
  pv_prev();           // PV(31)

  // lsum = oacc[4] row 64 -> held by lanes hi==0 at reg 0; broadcast by shfl
  const float inv0 = 1.0f / __shfl(oacc0[4][0], qi);
  const float inv1 = 1.0f / __shfl(oacc1[4][0], qi);

  // O^T: lane holds O[q][d = nd*16 + 4hi + r]
  u16* outp = attnout + (size_t)(b * SEQ + q0 + wid * 32 + qi) * MODELD + h * HDIM;
#pragma unroll
  for (int nd = 0; nd < 4; ++nd) {
    u32x2 ow;
    ow[0] = cvtpk(oacc0[nd][0] * inv0, oacc0[nd][1] * inv0);
    ow[1] = cvtpk(oacc0[nd][2] * inv0, oacc0[nd][3] * inv0);
    *(u32x2*)(outp + nd * 16 + hi * 4) = ow;
    u32x2 ow1;
    ow1[0] = cvtpk(oacc1[nd][0] * inv1, oacc1[nd][1] * inv1);
    ow1[1] = cvtpk(oacc1[nd][2] * inv1, oacc1[nd][3] * inv1);
    *(u32x2*)(outp + 16 * MODELD + nd * 16 + hi * 4) = ow1;
  }
}

// ---------------- launch ----------------
extern "C" void kernel_launch(void* const* d_in, const int* in_sizes, int n_in,
                              void* d_out, int out_size, void* d_ws, size_t ws_size,
                              hipStream_t stream) {
  const float* x       = (const float*)d_in[0];
  const unsigned int* mask = (const unsigned int*)d_in[1];
  const float* w_qkv   = (const float*)d_in[2];
  const float* wq_base = (const float*)d_in[3];
  const float* bq      = (const float*)d_in[4];
  const float* wq_A    = (const float*)d_in[5];
  const float* wq_B    = (const float*)d_in[6];
  const float* wv_base = (const float*)d_in[7];
  const float* bv      = (const float*)d_in[8];
  const float* wv_A    = (const float*)d_in[9];
  const float* wv_B    = (const float*)d_in[10];
  const float* w_out   = (const float*)d_in[11];
  const float* b_out   = (const float*)d_in[12];
  float* out = (float*)d_out;

  char* ws = (char*)d_ws;
  u16* xb      = (u16*)(ws);                 // 8 MB  (reused as attnout)
  u16* wcomb   = (u16*)(ws + 8388608);       // 6 MB
  u16* woutb   = (u16*)(ws + 14680064);      // 2 MB
  u16* qws     = (u16*)(ws + 16777216);      // 8 MB
  u16* kws     = (u16*)(ws + 25165824);      // 8 MB
  u16* vws     = (u16*)(ws + 33554432);      // 8 MB
  u16* vtws    = (u16*)(ws + 41943040);      // 8 MB
  float* biasc = (float*)(ws + 50331648);    // 12 KB
  u16* mbf     = (u16*)(ws + 50343936);      // 8 KB (bf16 1/0 mask)
  u16* attnout = xb;                          // xb dead after gemm_qkv

  prep_cast<<<4096, 256, 0, stream>>>(x, xb);          // 4M elems
  prep_cast<<<1024, 256, 0, stream>>>(w_out, woutb);   // 1M elems
  prep_mask<<<1, 1024, 0, stream>>>(mask, mbf);
  prep_w<<<3072, 256, 0, stream>>>(w_qkv, wq_base, bq, wq_A, wq_B,
                                   wv_base, bv, wv_A, wv_B, wcomb, biasc);

  gemm128<0><<<dim3(QKVCOLS / 128, MROWS / 128), 256, 0, stream>>>(
      xb, wcomb, biasc, qws, kws, vws, nullptr);

  transpose_v<<<dim3(SEQ / 64, 32), 256, 0, stream>>>(vws, mbf, vtws);

  flash_attn<<<512, 256, 0, stream>>>(qws, kws, vtws, mbf, attnout);

  gemm128<1><<<dim3(MODELD / 128, MROWS / 128), 256, 0, stream>>>(
      attnout, woutb, b_out, nullptr, nullptr, nullptr, out);
}